// Round 4
// baseline (1290.674 us; speedup 1.0000x reference)
//
#include <hip/hip_runtime.h>
#include <hip/hip_bf16.h>
#include <math.h>

typedef __hip_bfloat16 bf16;
typedef unsigned short u16;
typedef __bf16 bf16x8 __attribute__((ext_vector_type(8)));
typedef float f32x4 __attribute__((ext_vector_type(4)));

// ---------- helpers ----------
__device__ __forceinline__ float b2f(bf16 v) { return __bfloat162float(v); }
__device__ __forceinline__ bf16 f2b(float v) { return __float2bfloat16(v); }
__device__ __forceinline__ float bits2f(unsigned int u) {
    union { unsigned int i; float f; } w; w.i = u << 16; return w.f;
}
__device__ __forceinline__ u16 f2bits(float v) {
    union { bf16 h; u16 u; } w; w.h = __float2bfloat16(v); return w.u;
}
__device__ __forceinline__ void async16(void* lds, const void* g) {
    __builtin_amdgcn_global_load_lds(
        (const __attribute__((address_space(1))) unsigned int*)g,
        (__attribute__((address_space(3))) unsigned int*)lds, 16, 0, 0);
}

#define DEPTH 4
#define HEADS 8
#define DHEAD 64
#define DIM 512
#define MLPD 2048
#define RED 128
#define BB 8
#define PP 4
#define NN 256
#define ROWS (BB*PP*NN)          // 8192 tokens
#define XELEMS ((size_t)ROWS*DIM) // 4194304

// ---------- batched weight transpose+cast: W fp32 [D][K][N] -> WT bf16 [D][N][K] ----------
__global__ __launch_bounds__(256)
void wtrans_all(const float* __restrict__ W, u16* __restrict__ WT, int K, int N)
{
    __shared__ float T[32][33];
    const int l = blockIdx.z;
    W  += (size_t)l * K * N;
    WT += (size_t)l * N * K;
    const int tx = threadIdx.x & 31, ty = threadIdx.x >> 5; // ty 0..7
    const int n0 = blockIdx.x * 32, k0 = blockIdx.y * 32;
#pragma unroll
    for (int r = 0; r < 4; ++r)
        T[ty + r*8][tx] = W[(size_t)(k0 + ty + r*8) * N + n0 + tx];
    __syncthreads();
#pragma unroll
    for (int r = 0; r < 4; ++r)
        WT[(size_t)(n0 + ty + r*8) * K + k0 + tx] = f2bits(T[tx][ty + r*8]);
}

// ---------- double-buffered MFMA GEMM (2-phase): C = act(A @ WT^T + bias) [+res]
template<int BM, int BN, int BK, int WROWS, int WCOLS>
__global__ __launch_bounds__(256)
void gemm_db(const u16* __restrict__ A, const u16* __restrict__ WT,
             const float* __restrict__ bias, const float* __restrict__ res,
             void* __restrict__ Cv, int M, int N, int K, int act, int outf32)
{
    constexpr int KG  = BK/8;        // 16B k-groups per row
    constexpr int RPC = 512/BK;      // rows per 1KB staging chunk
    constexpr int NCA = BM*BK/512;   // A chunks
    constexpr int NCB = BN*BK/512;   // B chunks
    constexpr int CPT = (NCA+NCB)/4; // chunks per wave
    constexpr int WM = BM/WROWS, WN = BN/WCOLS;
    constexpr int AM = WM/16, AN = WN/16, KB = BK/32;

    __shared__ u16 As[2][BM*BK];
    __shared__ u16 Bs[2][BN*BK];
    const int tid = threadIdx.x, wave = tid >> 6, lane = tid & 63;
    const int bm = blockIdx.x * BM;
    const int bn = blockIdx.y * BN;
    const int wm = (wave / WCOLS) * WM, wn = (wave % WCOLS) * WN;
    const int lr = lane & 15, quad = lane >> 4;

    const int rowc = lane / KG;
    const int kgs  = ((lane & (KG-1)) ^ (KG == 4 ? ((rowc >> 1) & 3) : (rowc & 7))) * 8;

    auto stage = [&](int buf, int k0) {
#pragma unroll
        for (int t = 0; t < CPT; ++t) {
            const int c = wave*CPT + t;
            if (c < NCA)
                async16(&As[buf][c*512], A  + (size_t)(bm + c*RPC + rowc) * K + k0 + kgs);
            else
                async16(&Bs[buf][(c-NCA)*512], WT + (size_t)(bn + (c-NCA)*RPC + rowc) * K + k0 + kgs);
        }
    };

    f32x4 acc[AM][AN] = {};

    stage(0, 0);
    __syncthreads();

    const int NK = K / BK;
    for (int ki = 0; ki < NK; ++ki) {
        const int cur = ki & 1;
        if (ki + 1 < NK) stage(cur ^ 1, (ki + 1) * BK);

        bf16x8 af[AM][KB], bv[AN][KB];
#pragma unroll
        for (int i = 0; i < AM; ++i) {
            const int rA = wm + i*16 + lr;
            const int sw = (KG == 4 ? (((rA & 15) >> 1) & 3) : (rA & 7));
#pragma unroll
            for (int kb = 0; kb < KB; ++kb)
                af[i][kb] = *(const bf16x8*)(As[cur] + rA*BK + (((kb*4 + quad) ^ sw) * 8));
        }
#pragma unroll
        for (int j = 0; j < AN; ++j) {
            const int rB = wn + j*16 + lr;
            const int sw = (KG == 4 ? (((rB & 15) >> 1) & 3) : (rB & 7));
#pragma unroll
            for (int kb = 0; kb < KB; ++kb)
                bv[j][kb] = *(const bf16x8*)(Bs[cur] + rB*BK + (((kb*4 + quad) ^ sw) * 8));
        }
#pragma unroll
        for (int i = 0; i < AM; ++i)
#pragma unroll
            for (int j = 0; j < AN; ++j)
#pragma unroll
                for (int kb = 0; kb < KB; ++kb)
                    acc[i][j] = __builtin_amdgcn_mfma_f32_16x16x32_bf16(
                        af[i][kb], bv[j][kb], acc[i][j], 0, 0, 0);
        __syncthreads();
    }

#pragma unroll
    for (int i = 0; i < AM; ++i) {
        const int rowb = bm + wm + i*16 + quad*4;
#pragma unroll
        for (int j = 0; j < AN; ++j) {
            const int col = bn + wn + j*16 + lr;
            const float bvs = bias ? bias[col] : 0.f;
#pragma unroll
            for (int r = 0; r < 4; ++r) {
                float v = acc[i][j][r] + bvs;
                if (act == 1) v = 0.5f * v * (1.0f + erff(v * 0.70710678118f));
                else if (act == 2) v = 1.0f / (1.0f + __expf(-v));
                const size_t idx = (size_t)(rowb + r) * N + col;
                if (res) v += res[idx];
                if (outf32) ((float*)Cv)[idx] = v;
                else        ((u16*)Cv)[idx] = f2bits(v);
            }
        }
    }
}

// ---------- flatmm MFMA GEMM: A staged in LDS, B read DIRECT global->VGPR ----------
// AITER flatmm pattern (skinny-K GEMM): B (the weight, <=2MB) is L2-resident;
// each bv load = 16 rows x 64B = 16 fully-consumed cache lines. No Bs in LDS ->
// 32KB LDS, ~3 blocks/CU co-resident (m114 inter-block latency hiding).
template<int BM, int BN, int BK, int WROWS, int WCOLS>
__global__ __launch_bounds__(256)
void gemm_flat(const u16* __restrict__ A, const u16* __restrict__ WT,
               const float* __restrict__ bias, const float* __restrict__ res,
               void* __restrict__ Cv, int M, int N, int K, int act, int outf32)
{
    constexpr int KG  = BK/8;        // 16B k-groups per A row
    constexpr int RPC = 512/BK;      // rows per 1KB staging chunk
    constexpr int NCA = BM*BK/512;   // A chunks
    constexpr int CPT = NCA/4;       // A chunks per wave
    constexpr int WM = BM/WROWS, WN = BN/WCOLS;
    constexpr int AM = WM/16, AN = WN/16, KB = BK/32;

    __shared__ u16 As[2][BM*BK];
    const int tid = threadIdx.x, wave = tid >> 6, lane = tid & 63;
    const int bm = blockIdx.x * BM;
    const int bn = blockIdx.y * BN;
    const int wm = (wave / WCOLS) * WM, wn = (wave % WCOLS) * WN;
    const int lr = lane & 15, quad = lane >> 4;

    const int rowc = lane / KG;
    const int kgs  = ((lane & (KG-1)) ^ (KG == 4 ? ((rowc >> 1) & 3) : (rowc & 7))) * 8;

    auto stage = [&](int buf, int k0) {
#pragma unroll
        for (int t = 0; t < CPT; ++t) {
            const int c = wave*CPT + t;
            async16(&As[buf][c*512], A + (size_t)(bm + c*RPC + rowc) * K + k0 + kgs);
        }
    };

    // per-lane B row base pointers (hoisted; step adds BK each iter)
    const u16* Brow[AN];
#pragma unroll
    for (int j = 0; j < AN; ++j)
        Brow[j] = WT + (size_t)(bn + wn + j*16 + lr) * K + quad*8;

    f32x4 acc[AM][AN] = {};

    stage(0, 0);
    __syncthreads();

    const int NK = K / BK;
    for (int ki = 0; ki < NK; ++ki) {
        const int cur = ki & 1;
        if (ki + 1 < NK) stage(cur ^ 1, (ki + 1) * BK);

        // B fragments: direct global loads (L2-resident weight), no swizzle
        bf16x8 bv[AN][KB];
#pragma unroll
        for (int j = 0; j < AN; ++j)
#pragma unroll
            for (int kb = 0; kb < KB; ++kb)
                bv[j][kb] = *(const bf16x8*)(Brow[j] + ki*BK + kb*32);

        // A fragments from LDS (XOR-swizzled, verified layout)
        bf16x8 af[AM][KB];
#pragma unroll
        for (int i = 0; i < AM; ++i) {
            const int rA = wm + i*16 + lr;
            const int sw = (KG == 4 ? (((rA & 15) >> 1) & 3) : (rA & 7));
#pragma unroll
            for (int kb = 0; kb < KB; ++kb)
                af[i][kb] = *(const bf16x8*)(As[cur] + rA*BK + (((kb*4 + quad) ^ sw) * 8));
        }
#pragma unroll
        for (int i = 0; i < AM; ++i)
#pragma unroll
            for (int j = 0; j < AN; ++j)
#pragma unroll
                for (int kb = 0; kb < KB; ++kb)
                    acc[i][j] = __builtin_amdgcn_mfma_f32_16x16x32_bf16(
                        af[i][kb], bv[j][kb], acc[i][j], 0, 0, 0);
        __syncthreads();
    }

#pragma unroll
    for (int i = 0; i < AM; ++i) {
        const int rowb = bm + wm + i*16 + quad*4;
#pragma unroll
        for (int j = 0; j < AN; ++j) {
            const int col = bn + wn + j*16 + lr;
            const float bvs = bias ? bias[col] : 0.f;
#pragma unroll
            for (int r = 0; r < 4; ++r) {
                float v = acc[i][j][r] + bvs;
                if (act == 1) v = 0.5f * v * (1.0f + erff(v * 0.70710678118f));
                else if (act == 2) v = 1.0f / (1.0f + __expf(-v));
                const size_t idx = (size_t)(rowb + r) * N + col;
                if (res) v += res[idx];
                if (outf32) ((float*)Cv)[idx] = v;
                else        ((u16*)Cv)[idx] = f2bits(v);
            }
        }
    }
}

// ---------- MFMA flash attention: one block per (b,p,h), wave = 64 query rows ----------
__global__ __launch_bounds__(256)
void attn_mfma(const u16* __restrict__ qkv, u16* __restrict__ out)
{
    __shared__ u16 Kt[64*72];
    __shared__ u16 Vt[64*72];
    __shared__ u16 Pw[4][64*72];
    const int tid = threadIdx.x;
    const int wave = tid >> 6, lane = tid & 63;
    const int lr = lane & 15, quad = lane >> 4;
    const int bp = blockIdx.x >> 3, h = blockIdx.x & 7;
    const u16* base = qkv + (size_t)bp * NN * (3*DIM);
    const int qo = h*DHEAD, ko = DIM + h*DHEAD, vo = 2*DIM + h*DHEAD;
    const int m0 = wave * 64;

    bf16x8 qf[4][2];
#pragma unroll
    for (int i = 0; i < 4; ++i)
#pragma unroll
        for (int kb = 0; kb < 2; ++kb)
            qf[i][kb] = *(const bf16x8*)(base + (size_t)(m0 + i*16 + lr)*(3*DIM)
                                         + qo + kb*32 + quad*8);

    f32x4 o[4][4] = {};
    float mrow[4][4], lrow[4][4];
#pragma unroll
    for (int i = 0; i < 4; ++i)
#pragma unroll
        for (int r = 0; r < 4; ++r) { mrow[i][r] = -1e30f; lrow[i][r] = 0.f; }

    const int sr = tid >> 3, sc = tid & 7;

    for (int t = 0; t < 4; ++t) {
        __syncthreads();
#pragma unroll
        for (int half = 0; half < 2; ++half) {
            const int key = half*32 + sr;
            const u16* krow = base + (size_t)(t*64 + key)*(3*DIM);
            uint4 kv = *(const uint4*)(krow + ko + sc*8);
            *(uint4*)(Kt + key*72 + sc*8) = kv;
            uint4 vv = *(const uint4*)(krow + vo + sc*8);
            const int d0 = sc*8;
            Vt[(d0+0)*72 + key] = (u16)(vv.x & 0xffffu);
            Vt[(d0+1)*72 + key] = (u16)(vv.x >> 16);
            Vt[(d0+2)*72 + key] = (u16)(vv.y & 0xffffu);
            Vt[(d0+3)*72 + key] = (u16)(vv.y >> 16);
            Vt[(d0+4)*72 + key] = (u16)(vv.z & 0xffffu);
            Vt[(d0+5)*72 + key] = (u16)(vv.z >> 16);
            Vt[(d0+6)*72 + key] = (u16)(vv.w & 0xffffu);
            Vt[(d0+7)*72 + key] = (u16)(vv.w >> 16);
        }
        __syncthreads();

        f32x4 s[4][4] = {};
        bf16x8 kf[4][2];
#pragma unroll
        for (int j = 0; j < 4; ++j)
#pragma unroll
            for (int kb = 0; kb < 2; ++kb)
                kf[j][kb] = *(const bf16x8*)(Kt + (j*16 + lr)*72 + kb*32 + quad*8);
#pragma unroll
        for (int i = 0; i < 4; ++i)
#pragma unroll
            for (int j = 0; j < 4; ++j)
#pragma unroll
                for (int kb = 0; kb < 2; ++kb)
                    s[i][j] = __builtin_amdgcn_mfma_f32_16x16x32_bf16(
                        qf[i][kb], kf[j][kb], s[i][j], 0, 0, 0);

        float alpha[4][4];
#pragma unroll
        for (int i = 0; i < 4; ++i)
#pragma unroll
            for (int r = 0; r < 4; ++r) {
#pragma unroll
                for (int j = 0; j < 4; ++j) s[i][j][r] *= 0.125f;
                float mt = fmaxf(fmaxf(s[i][0][r], s[i][1][r]),
                                 fmaxf(s[i][2][r], s[i][3][r]));
#pragma unroll
                for (int off = 1; off <= 8; off <<= 1) mt = fmaxf(mt, __shfl_xor(mt, off));
                const float mn = fmaxf(mrow[i][r], mt);
                alpha[i][r] = __expf(mrow[i][r] - mn);
                mrow[i][r] = mn;
                float ssum = 0.f;
#pragma unroll
                for (int j = 0; j < 4; ++j) {
                    const float p = __expf(s[i][j][r] - mn);
                    s[i][j][r] = p; ssum += p;
                }
#pragma unroll
                for (int off = 1; off <= 8; off <<= 1) ssum += __shfl_xor(ssum, off);
                lrow[i][r] = lrow[i][r]*alpha[i][r] + ssum;
            }

#pragma unroll
        for (int i = 0; i < 4; ++i)
#pragma unroll
            for (int j = 0; j < 4; ++j)
#pragma unroll
                for (int r = 0; r < 4; ++r)
                    Pw[wave][(i*16 + quad*4 + r)*72 + j*16 + lr] = f2bits(s[i][j][r]);
        __syncthreads();

#pragma unroll
        for (int i = 0; i < 4; ++i)
#pragma unroll
            for (int jd = 0; jd < 4; ++jd)
#pragma unroll
                for (int r = 0; r < 4; ++r)
                    o[i][jd][r] *= alpha[i][r];

        bf16x8 af[4][2], bv[4][2];
#pragma unroll
        for (int i = 0; i < 4; ++i)
#pragma unroll
            for (int kb = 0; kb < 2; ++kb)
                af[i][kb] = *(const bf16x8*)(Pw[wave] + (i*16 + lr)*72 + kb*32 + quad*8);
#pragma unroll
        for (int jd = 0; jd < 4; ++jd)
#pragma unroll
            for (int kb = 0; kb < 2; ++kb)
                bv[jd][kb] = *(const bf16x8*)(Vt + (jd*16 + lr)*72 + kb*32 + quad*8);
#pragma unroll
        for (int i = 0; i < 4; ++i)
#pragma unroll
            for (int jd = 0; jd < 4; ++jd)
#pragma unroll
                for (int kb = 0; kb < 2; ++kb)
                    o[i][jd] = __builtin_amdgcn_mfma_f32_16x16x32_bf16(
                        af[i][kb], bv[jd][kb], o[i][jd], 0, 0, 0);
    }

#pragma unroll
    for (int i = 0; i < 4; ++i)
#pragma unroll
        for (int r = 0; r < 4; ++r) {
            const float inv = 1.0f / lrow[i][r];
            const size_t rowg = (size_t)bp*NN + m0 + i*16 + quad*4 + r;
#pragma unroll
            for (int jd = 0; jd < 4; ++jd)
                out[rowg*DIM + h*DHEAD + jd*16 + lr] = f2bits(o[i][jd][r] * inv);
        }
}

// ---------- LayerNorm over DIM=512, fp32 in, bf16 out; one wave per row; float4 ----------
__global__ __launch_bounds__(256)
void ln_kernel(const float* __restrict__ x, const float* __restrict__ g,
               const float* __restrict__ b, u16* __restrict__ y, int rows)
{
    const int wave = threadIdx.x >> 6, lane = threadIdx.x & 63;
    const int row = blockIdx.x * 4 + wave;
    if (row >= rows) return;
    const float4* xr = (const float4*)(x + (size_t)row * DIM);
    float4 v0 = xr[lane], v1 = xr[lane + 64];
    float s  = v0.x+v0.y+v0.z+v0.w + v1.x+v1.y+v1.z+v1.w;
    float s2 = v0.x*v0.x+v0.y*v0.y+v0.z*v0.z+v0.w*v0.w
             + v1.x*v1.x+v1.y*v1.y+v1.z*v1.z+v1.w*v1.w;
#pragma unroll
    for (int off = 32; off; off >>= 1) { s += __shfl_xor(s, off); s2 += __shfl_xor(s2, off); }
    const float mean = s * (1.f/512.f);
    const float var  = s2 * (1.f/512.f) - mean*mean;
    const float rstd = rsqrtf(var + 1e-5f);
    const float4* gp = (const float4*)g; const float4* bp = (const float4*)b;
    float4 g0 = gp[lane], g1 = gp[lane+64], b0 = bp[lane], b1 = bp[lane+64];
    ushort4 o0, o1;
    o0.x = f2bits((v0.x-mean)*rstd*g0.x + b0.x);
    o0.y = f2bits((v0.y-mean)*rstd*g0.y + b0.y);
    o0.z = f2bits((v0.z-mean)*rstd*g0.z + b0.z);
    o0.w = f2bits((v0.w-mean)*rstd*g0.w + b0.w);
    o1.x = f2bits((v1.x-mean)*rstd*g1.x + b1.x);
    o1.y = f2bits((v1.y-mean)*rstd*g1.y + b1.y);
    o1.z = f2bits((v1.z-mean)*rstd*g1.z + b1.z);
    o1.w = f2bits((v1.w-mean)*rstd*g1.w + b1.w);
    ushort4* yr = (ushort4*)(y + (size_t)row * DIM);
    yr[lane] = o0; yr[lane+64] = o1;
}

// ---------- mean over P: [b,p,n,d] -> [b,n,d], 4 elems/thread ----------
__global__ void mean_kernel(const u16* __restrict__ L, u16* __restrict__ G)
{
    const int idx = blockIdx.x * 256 + threadIdx.x;   // < 8*256*512/4
    const int b = idx >> 15;
    const int rem = idx & 32767;
    float a0 = 0.f, a1 = 0.f, a2 = 0.f, a3 = 0.f;
#pragma unroll
    for (int p = 0; p < PP; ++p) {
        ushort4 u = *(const ushort4*)(L + ((size_t)b*PP + p)*131072 + rem*4);
        a0 += bits2f(u.x); a1 += bits2f(u.y); a2 += bits2f(u.z); a3 += bits2f(u.w);
    }
    ushort4 o;
    o.x = f2bits(0.25f*a0); o.y = f2bits(0.25f*a1);
    o.z = f2bits(0.25f*a2); o.w = f2bits(0.25f*a3);
    *(ushort4*)(G + (size_t)idx*4) = o;
}

// ---------- s_attn: sigmoid( [xl, xg] . ws + bs ), one wave per row ----------
__global__ __launch_bounds__(256)
void sattn_kernel(const u16* __restrict__ xl, const u16* __restrict__ xg,
                  const float* __restrict__ wsv, const float* __restrict__ bs,
                  float* __restrict__ S)
{
    const int wave = threadIdx.x >> 6, lane = threadIdx.x & 63;
    const int row = blockIdx.x * 4 + wave;
    const int b = row >> 10;
    const int n = row & 255;
    const u16* xlr = xl + (size_t)row * RED;
    const u16* xgr = xg + ((size_t)b*NN + n) * RED;
    float s = bits2f(xlr[lane])    * wsv[lane]
            + bits2f(xlr[lane+64]) * wsv[lane+64]
            + bits2f(xgr[lane])    * wsv[RED+lane]
            + bits2f(xgr[lane+64]) * wsv[RED+64+lane];
#pragma unroll
    for (int off = 32; off; off >>= 1) s += __shfl_xor(s, off);
    if (lane == 0) S[row] = 1.f / (1.f + __expf(-(s + bs[0])));
}

// ---------- fuse: x_new = x_attn_res + mlp_out * c_attn * s_attn (4 elems/thread) ----------
__global__ void fuse_kernel(const float4* __restrict__ xb, const float4* __restrict__ m1,
                            const u16* __restrict__ ca, const float* __restrict__ S,
                            float4* __restrict__ xa)
{
    const int idx = blockIdx.x * 256 + threadIdx.x;   // < XELEMS/4
    const int r = idx >> 7;          // 128 float4-groups per row
    const int dg = idx & 127;
    const int b = r >> 10;
    const int n = r & 255;
    const float s = S[r];
    ushort4 cu = *(const ushort4*)(ca + ((((size_t)b << 8) + n)*DIM) + dg*4);
    float4 xv = xb[idx], mv = m1[idx], o;
    o.x = xv.x + mv.x * bits2f(cu.x) * s;
    o.y = xv.y + mv.y * bits2f(cu.y) * s;
    o.z = xv.z + mv.z * bits2f(cu.z) * s;
    o.w = xv.w + mv.w * bits2f(cu.w) * s;
    xa[idx] = o;
}

// ---------- host launch ----------
extern "C" void kernel_launch(void* const* d_in, const int* in_sizes, int n_in,
                              void* d_out, int out_size, void* d_ws, size_t ws_size,
                              hipStream_t stream)
{
    const float* x_in  = (const float*)d_in[0];
    const float* ln1_g = (const float*)d_in[1];
    const float* ln1_b = (const float*)d_in[2];
    const float* w_qkv = (const float*)d_in[3];
    const float* w_o   = (const float*)d_in[4];
    const float* b_o   = (const float*)d_in[5];
    const float* ln2_g = (const float*)d_in[6];
    const float* ln2_b = (const float*)d_in[7];
    const float* w1    = (const float*)d_in[8];
    const float* b1    = (const float*)d_in[9];
    const float* w2    = (const float*)d_in[10];
    const float* b2    = (const float*)d_in[11];
    const float* bn_g  = (const float*)d_in[12];
    const float* bn_b  = (const float*)d_in[13];
    const float* wg    = (const float*)d_in[14];
    const float* bg    = (const float*)d_in[15];
    const float* wl    = (const float*)d_in[16];
    const float* bl    = (const float*)d_in[17];
    const float* wc    = (const float*)d_in[18];
    const float* bc    = (const float*)d_in[19];
    const float* wsw   = (const float*)d_in[20];
    const float* bsb   = (const float*)d_in[21];

    char* ws = (char*)d_ws;
    auto alloc = [&](size_t bytes) {
        char* p = ws;
        ws += (bytes + 255) & ~(size_t)255;
        return p;
    };
    float* XA = (float*)alloc(XELEMS * 4);
    float* XB = (float*)alloc(XELEMS * 4);
    float* M1 = (float*)alloc(XELEMS * 4);
    u16*   L  = (u16*)  alloc(XELEMS * 2);
    u16*   Q  = (u16*)  alloc((size_t)ROWS * 3*DIM * 2);
    u16*   H  = (u16*)  alloc((size_t)ROWS * MLPD * 2);
    u16*   G  = (u16*)  alloc((size_t)BB*NN*DIM * 2);
    u16*   G2 = (u16*)  alloc((size_t)BB*NN*RED * 2);
    u16*   XL = (u16*)  alloc((size_t)ROWS*RED * 2);
    u16*   CA = (u16*)  alloc((size_t)BB*NN*DIM * 2);
    float* S  = (float*)alloc((size_t)ROWS * 4);
    // all-layer transposed bf16 weights
    u16* WTqkv = (u16*)alloc((size_t)DEPTH*DIM*3*DIM * 2);
    u16* WTo   = (u16*)alloc((size_t)DEPTH*DIM*DIM * 2);
    u16* WT1   = (u16*)alloc((size_t)DEPTH*DIM*MLPD * 2);
    u16* WT2   = (u16*)alloc((size_t)DEPTH*MLPD*DIM * 2);
    u16* WTl   = (u16*)alloc((size_t)DEPTH*DIM*RED * 2);
    u16* WTg   = (u16*)alloc((size_t)DEPTH*DIM*RED * 2);
    u16* WTc   = (u16*)alloc((size_t)DEPTH*RED*DIM * 2);

    // ---- all weight transposes upfront, batched over depth ----
    wtrans_all<<<dim3(48,16,DEPTH), 256, 0, stream>>>(w_qkv, WTqkv, DIM, 3*DIM);
    wtrans_all<<<dim3(16,16,DEPTH), 256, 0, stream>>>(w_o,   WTo,   DIM, DIM);
    wtrans_all<<<dim3(64,16,DEPTH), 256, 0, stream>>>(w1,    WT1,   DIM, MLPD);
    wtrans_all<<<dim3(16,64,DEPTH), 256, 0, stream>>>(w2,    WT2,   MLPD, DIM);
    wtrans_all<<<dim3(4,16,DEPTH),  256, 0, stream>>>(wl,    WTl,   DIM, RED);
    wtrans_all<<<dim3(4,16,DEPTH),  256, 0, stream>>>(wg,    WTg,   DIM, RED);
    wtrans_all<<<dim3(16,4,DEPTH),  256, 0, stream>>>(wc,    WTc,   RED, DIM);

    for (int l = 0; l < DEPTH; ++l) {
        const float* Xres = l ? (const float*)XA : x_in;   // layer-0 reads input directly
        // ---- attention block ----
        ln_kernel<<<ROWS/4, 256, 0, stream>>>(Xres, ln1_g + l*DIM, ln1_b + l*DIM, L, ROWS);
        gemm_flat<128,128,64,2,2><<<dim3(64,12), 256, 0, stream>>>(
            L, WTqkv + (size_t)l*DIM*3*DIM, nullptr, nullptr, Q, ROWS, 3*DIM, DIM, 0, 0);
        attn_mfma<<<BB*PP*HEADS, 256, 0, stream>>>(Q, L);
        gemm_flat<128,128,64,2,2><<<dim3(64,4), 256, 0, stream>>>(
            L, WTo + (size_t)l*DIM*DIM, b_o + l*DIM, Xres, XB, ROWS, DIM, DIM, 0, 1);

        // ---- MLP ----
        ln_kernel<<<ROWS/4, 256, 0, stream>>>(XB, ln2_g + l*DIM, ln2_b + l*DIM, Q, ROWS);
        gemm_flat<128,128,64,2,2><<<dim3(64,16), 256, 0, stream>>>(
            Q, WT1 + (size_t)l*DIM*MLPD, b1 + l*MLPD, nullptr, H, ROWS, MLPD, DIM, 1, 0);
        gemm_flat<128,128,64,2,2><<<dim3(64,4), 256, 0, stream>>>(
            H, WT2 + (size_t)l*MLPD*DIM, b2 + l*DIM, nullptr, M1, ROWS, DIM, MLPD, 0, 1);

        // ---- BiAttn ----
        ln_kernel<<<ROWS/4, 256, 0, stream>>>(M1, bn_g + l*DIM, bn_b + l*DIM, L, ROWS);
        mean_kernel<<<(BB*NN*DIM)/1024, 256, 0, stream>>>(L, G);
        gemm_db<64,64,64,2,2><<<dim3(32,2), 256, 0, stream>>>(
            G, WTg + (size_t)l*DIM*RED, bg + l*RED, nullptr, G2, BB*NN, RED, DIM, 1, 0);
        gemm_db<64,64,64,2,2><<<dim3(128,2), 256, 0, stream>>>(
            L, WTl + (size_t)l*DIM*RED, bl + l*RED, nullptr, XL, ROWS, RED, DIM, 1, 0);
        gemm_db<64,64,64,2,2><<<dim3(32,8), 256, 0, stream>>>(
            G2, WTc + (size_t)l*RED*DIM, bc + l*DIM, nullptr, CA, BB*NN, DIM, RED, 2, 0);
        sattn_kernel<<<ROWS/4, 256, 0, stream>>>(XL, G2, wsw + (size_t)l*2*RED, bsb + l, S);
        // last layer writes the fp32 output buffer directly (drops final copy)
        fuse_kernel<<<XELEMS/1024, 256, 0, stream>>>((const float4*)XB, (const float4*)M1,
                                                     CA, S,
                                                     (l == DEPTH-1) ? (float4*)d_out
                                                                    : (float4*)XA);
    }
}

// Round 5
// 1026.875 us; speedup vs baseline: 1.2569x; 1.2569x over previous
//
#include <hip/hip_runtime.h>
#include <hip/hip_bf16.h>
#include <math.h>

typedef __hip_bfloat16 bf16;
typedef unsigned short u16;
typedef __bf16 bf16x8 __attribute__((ext_vector_type(8)));
typedef float f32x4 __attribute__((ext_vector_type(4)));

// ---------- helpers ----------
__device__ __forceinline__ float b2f(bf16 v) { return __bfloat162float(v); }
__device__ __forceinline__ bf16 f2b(float v) { return __float2bfloat16(v); }
__device__ __forceinline__ float bits2f(unsigned int u) {
    union { unsigned int i; float f; } w; w.i = u << 16; return w.f;
}
__device__ __forceinline__ u16 f2bits(float v) {
    union { bf16 h; u16 u; } w; w.h = __float2bfloat16(v); return w.u;
}
__device__ __forceinline__ void async16(void* lds, const void* g) {
    __builtin_amdgcn_global_load_lds(
        (const __attribute__((address_space(1))) unsigned int*)g,
        (__attribute__((address_space(3))) unsigned int*)lds, 16, 0, 0);
}

#define DEPTH 4
#define HEADS 8
#define DHEAD 64
#define DIM 512
#define MLPD 2048
#define RED 128
#define BB 8
#define PP 4
#define NN 256
#define ROWS (BB*PP*NN)          // 8192 tokens
#define XELEMS ((size_t)ROWS*DIM) // 4194304

// ---------- batched weight transpose+cast: W fp32 [D][K][N] -> WT bf16 [D][N][K] ----------
__global__ __launch_bounds__(256)
void wtrans_all(const float* __restrict__ W, u16* __restrict__ WT, int K, int N)
{
    __shared__ float T[32][33];
    const int l = blockIdx.z;
    W  += (size_t)l * K * N;
    WT += (size_t)l * N * K;
    const int tx = threadIdx.x & 31, ty = threadIdx.x >> 5; // ty 0..7
    const int n0 = blockIdx.x * 32, k0 = blockIdx.y * 32;
#pragma unroll
    for (int r = 0; r < 4; ++r)
        T[ty + r*8][tx] = W[(size_t)(k0 + ty + r*8) * N + n0 + tx];
    __syncthreads();
#pragma unroll
    for (int r = 0; r < 4; ++r)
        WT[(size_t)(n0 + ty + r*8) * K + k0 + tx] = f2bits(T[tx][ty + r*8]);
}

// ---------- double-buffered MFMA GEMM (2-phase) with XCD-aware block swizzle ----------
// C = act(A @ WT^T + bias) [+res]. 1-D grid, nwg = (M/BM)*(N/BN), nwg % 8 == 0.
// Swizzle: xcd = bid&7 gets a CONTIGUOUS chunk of M-major tile ids -> each XCD's
// A-panels + whole B stay in its private 4MB L2 (staging latency L3->L2).
template<int BM, int BN, int BK, int WROWS, int WCOLS>
__global__ __launch_bounds__(256)
void gemm_db(const u16* __restrict__ A, const u16* __restrict__ WT,
             const float* __restrict__ bias, const float* __restrict__ res,
             void* __restrict__ Cv, int M, int N, int K, int act, int outf32)
{
    constexpr int KG  = BK/8;        // 16B k-groups per row
    constexpr int RPC = 512/BK;      // rows per 1KB staging chunk
    constexpr int NCA = BM*BK/512;   // A chunks
    constexpr int NCB = BN*BK/512;   // B chunks
    constexpr int CPT = (NCA+NCB)/4; // chunks per wave
    constexpr int WM = BM/WROWS, WN = BN/WCOLS;
    constexpr int AM = WM/16, AN = WN/16, KB = BK/32;

    __shared__ u16 As[2][BM*BK];
    __shared__ u16 Bs[2][BN*BK];
    const int tid = threadIdx.x, wave = tid >> 6, lane = tid & 63;

    // bijective XCD swizzle (nwg % 8 == 0 for all our launches)
    const int nwg = gridDim.x;
    const int wg  = (blockIdx.x & 7) * (nwg >> 3) + (blockIdx.x >> 3);
    const int NT  = N / BN;
    const int bm = (wg / NT) * BM;
    const int bn = (wg % NT) * BN;

    const int wm = (wave / WCOLS) * WM, wn = (wave % WCOLS) * WN;
    const int lr = lane & 15, quad = lane >> 4;

    const int rowc = lane / KG;
    const int kgs  = ((lane & (KG-1)) ^ (KG == 4 ? ((rowc >> 1) & 3) : (rowc & 7))) * 8;

    auto stage = [&](int buf, int k0) {
#pragma unroll
        for (int t = 0; t < CPT; ++t) {
            const int c = wave*CPT + t;
            if (c < NCA)
                async16(&As[buf][c*512], A  + (size_t)(bm + c*RPC + rowc) * K + k0 + kgs);
            else
                async16(&Bs[buf][(c-NCA)*512], WT + (size_t)(bn + (c-NCA)*RPC + rowc) * K + k0 + kgs);
        }
    };

    f32x4 acc[AM][AN] = {};

    stage(0, 0);
    __syncthreads();

    const int NK = K / BK;
    for (int ki = 0; ki < NK; ++ki) {
        const int cur = ki & 1;
        if (ki + 1 < NK) stage(cur ^ 1, (ki + 1) * BK);

        bf16x8 af[AM][KB], bv[AN][KB];
#pragma unroll
        for (int i = 0; i < AM; ++i) {
            const int rA = wm + i*16 + lr;
            const int sw = (KG == 4 ? (((rA & 15) >> 1) & 3) : (rA & 7));
#pragma unroll
            for (int kb = 0; kb < KB; ++kb)
                af[i][kb] = *(const bf16x8*)(As[cur] + rA*BK + (((kb*4 + quad) ^ sw) * 8));
        }
#pragma unroll
        for (int j = 0; j < AN; ++j) {
            const int rB = wn + j*16 + lr;
            const int sw = (KG == 4 ? (((rB & 15) >> 1) & 3) : (rB & 7));
#pragma unroll
            for (int kb = 0; kb < KB; ++kb)
                bv[j][kb] = *(const bf16x8*)(Bs[cur] + rB*BK + (((kb*4 + quad) ^ sw) * 8));
        }
#pragma unroll
        for (int i = 0; i < AM; ++i)
#pragma unroll
            for (int j = 0; j < AN; ++j)
#pragma unroll
                for (int kb = 0; kb < KB; ++kb)
                    acc[i][j] = __builtin_amdgcn_mfma_f32_16x16x32_bf16(
                        af[i][kb], bv[j][kb], acc[i][j], 0, 0, 0);
        __syncthreads();
    }

#pragma unroll
    for (int i = 0; i < AM; ++i) {
        const int rowb = bm + wm + i*16 + quad*4;
#pragma unroll
        for (int j = 0; j < AN; ++j) {
            const int col = bn + wn + j*16 + lr;
            const float bvs = bias ? bias[col] : 0.f;
#pragma unroll
            for (int r = 0; r < 4; ++r) {
                float v = acc[i][j][r] + bvs;
                if (act == 1) v = 0.5f * v * (1.0f + erff(v * 0.70710678118f));
                else if (act == 2) v = 1.0f / (1.0f + __expf(-v));
                const size_t idx = (size_t)(rowb + r) * N + col;
                if (res) v += res[idx];
                if (outf32) ((float*)Cv)[idx] = v;
                else        ((u16*)Cv)[idx] = f2bits(v);
            }
        }
    }
}

// ---------- MFMA flash attention: one block per (b,p,h), wave = 64 query rows ----------
__global__ __launch_bounds__(256)
void attn_mfma(const u16* __restrict__ qkv, u16* __restrict__ out)
{
    __shared__ u16 Kt[64*72];
    __shared__ u16 Vt[64*72];
    __shared__ u16 Pw[4][64*72];
    const int tid = threadIdx.x;
    const int wave = tid >> 6, lane = tid & 63;
    const int lr = lane & 15, quad = lane >> 4;
    const int bp = blockIdx.x >> 3, h = blockIdx.x & 7;
    const u16* base = qkv + (size_t)bp * NN * (3*DIM);
    const int qo = h*DHEAD, ko = DIM + h*DHEAD, vo = 2*DIM + h*DHEAD;
    const int m0 = wave * 64;

    bf16x8 qf[4][2];
#pragma unroll
    for (int i = 0; i < 4; ++i)
#pragma unroll
        for (int kb = 0; kb < 2; ++kb)
            qf[i][kb] = *(const bf16x8*)(base + (size_t)(m0 + i*16 + lr)*(3*DIM)
                                         + qo + kb*32 + quad*8);

    f32x4 o[4][4] = {};
    float mrow[4][4], lrow[4][4];
#pragma unroll
    for (int i = 0; i < 4; ++i)
#pragma unroll
        for (int r = 0; r < 4; ++r) { mrow[i][r] = -1e30f; lrow[i][r] = 0.f; }

    const int sr = tid >> 3, sc = tid & 7;

    for (int t = 0; t < 4; ++t) {
        __syncthreads();
#pragma unroll
        for (int half = 0; half < 2; ++half) {
            const int key = half*32 + sr;
            const u16* krow = base + (size_t)(t*64 + key)*(3*DIM);
            uint4 kv = *(const uint4*)(krow + ko + sc*8);
            *(uint4*)(Kt + key*72 + sc*8) = kv;
            uint4 vv = *(const uint4*)(krow + vo + sc*8);
            const int d0 = sc*8;
            Vt[(d0+0)*72 + key] = (u16)(vv.x & 0xffffu);
            Vt[(d0+1)*72 + key] = (u16)(vv.x >> 16);
            Vt[(d0+2)*72 + key] = (u16)(vv.y & 0xffffu);
            Vt[(d0+3)*72 + key] = (u16)(vv.y >> 16);
            Vt[(d0+4)*72 + key] = (u16)(vv.z & 0xffffu);
            Vt[(d0+5)*72 + key] = (u16)(vv.z >> 16);
            Vt[(d0+6)*72 + key] = (u16)(vv.w & 0xffffu);
            Vt[(d0+7)*72 + key] = (u16)(vv.w >> 16);
        }
        __syncthreads();

        f32x4 s[4][4] = {};
        bf16x8 kf[4][2];
#pragma unroll
        for (int j = 0; j < 4; ++j)
#pragma unroll
            for (int kb = 0; kb < 2; ++kb)
                kf[j][kb] = *(const bf16x8*)(Kt + (j*16 + lr)*72 + kb*32 + quad*8);
#pragma unroll
        for (int i = 0; i < 4; ++i)
#pragma unroll
            for (int j = 0; j < 4; ++j)
#pragma unroll
                for (int kb = 0; kb < 2; ++kb)
                    s[i][j] = __builtin_amdgcn_mfma_f32_16x16x32_bf16(
                        qf[i][kb], kf[j][kb], s[i][j], 0, 0, 0);

        float alpha[4][4];
#pragma unroll
        for (int i = 0; i < 4; ++i)
#pragma unroll
            for (int r = 0; r < 4; ++r) {
#pragma unroll
                for (int j = 0; j < 4; ++j) s[i][j][r] *= 0.125f;
                float mt = fmaxf(fmaxf(s[i][0][r], s[i][1][r]),
                                 fmaxf(s[i][2][r], s[i][3][r]));
#pragma unroll
                for (int off = 1; off <= 8; off <<= 1) mt = fmaxf(mt, __shfl_xor(mt, off));
                const float mn = fmaxf(mrow[i][r], mt);
                alpha[i][r] = __expf(mrow[i][r] - mn);
                mrow[i][r] = mn;
                float ssum = 0.f;
#pragma unroll
                for (int j = 0; j < 4; ++j) {
                    const float p = __expf(s[i][j][r] - mn);
                    s[i][j][r] = p; ssum += p;
                }
#pragma unroll
                for (int off = 1; off <= 8; off <<= 1) ssum += __shfl_xor(ssum, off);
                lrow[i][r] = lrow[i][r]*alpha[i][r] + ssum;
            }

#pragma unroll
        for (int i = 0; i < 4; ++i)
#pragma unroll
            for (int j = 0; j < 4; ++j)
#pragma unroll
                for (int r = 0; r < 4; ++r)
                    Pw[wave][(i*16 + quad*4 + r)*72 + j*16 + lr] = f2bits(s[i][j][r]);
        __syncthreads();

#pragma unroll
        for (int i = 0; i < 4; ++i)
#pragma unroll
            for (int jd = 0; jd < 4; ++jd)
#pragma unroll
                for (int r = 0; r < 4; ++r)
                    o[i][jd][r] *= alpha[i][r];

        bf16x8 af[4][2], bv[4][2];
#pragma unroll
        for (int i = 0; i < 4; ++i)
#pragma unroll
            for (int kb = 0; kb < 2; ++kb)
                af[i][kb] = *(const bf16x8*)(Pw[wave] + (i*16 + lr)*72 + kb*32 + quad*8);
#pragma unroll
        for (int jd = 0; jd < 4; ++jd)
#pragma unroll
            for (int kb = 0; kb < 2; ++kb)
                bv[jd][kb] = *(const bf16x8*)(Vt + (jd*16 + lr)*72 + kb*32 + quad*8);
#pragma unroll
        for (int i = 0; i < 4; ++i)
#pragma unroll
            for (int jd = 0; jd < 4; ++jd)
#pragma unroll
                for (int kb = 0; kb < 2; ++kb)
                    o[i][jd] = __builtin_amdgcn_mfma_f32_16x16x32_bf16(
                        af[i][kb], bv[jd][kb], o[i][jd], 0, 0, 0);
    }

#pragma unroll
    for (int i = 0; i < 4; ++i)
#pragma unroll
        for (int r = 0; r < 4; ++r) {
            const float inv = 1.0f / lrow[i][r];
            const size_t rowg = (size_t)bp*NN + m0 + i*16 + quad*4 + r;
#pragma unroll
            for (int jd = 0; jd < 4; ++jd)
                out[rowg*DIM + h*DHEAD + jd*16 + lr] = f2bits(o[i][jd][r] * inv);
        }
}

// ---------- LayerNorm over DIM=512, fp32 in, bf16 out; one wave per row; float4 ----------
__global__ __launch_bounds__(256)
void ln_kernel(const float* __restrict__ x, const float* __restrict__ g,
               const float* __restrict__ b, u16* __restrict__ y, int rows)
{
    const int wave = threadIdx.x >> 6, lane = threadIdx.x & 63;
    const int row = blockIdx.x * 4 + wave;
    if (row >= rows) return;
    const float4* xr = (const float4*)(x + (size_t)row * DIM);
    float4 v0 = xr[lane], v1 = xr[lane + 64];
    float s  = v0.x+v0.y+v0.z+v0.w + v1.x+v1.y+v1.z+v1.w;
    float s2 = v0.x*v0.x+v0.y*v0.y+v0.z*v0.z+v0.w*v0.w
             + v1.x*v1.x+v1.y*v1.y+v1.z*v1.z+v1.w*v1.w;
#pragma unroll
    for (int off = 32; off; off >>= 1) { s += __shfl_xor(s, off); s2 += __shfl_xor(s2, off); }
    const float mean = s * (1.f/512.f);
    const float var  = s2 * (1.f/512.f) - mean*mean;
    const float rstd = rsqrtf(var + 1e-5f);
    const float4* gp = (const float4*)g; const float4* bp = (const float4*)b;
    float4 g0 = gp[lane], g1 = gp[lane+64], b0 = bp[lane], b1 = bp[lane+64];
    ushort4 o0, o1;
    o0.x = f2bits((v0.x-mean)*rstd*g0.x + b0.x);
    o0.y = f2bits((v0.y-mean)*rstd*g0.y + b0.y);
    o0.z = f2bits((v0.z-mean)*rstd*g0.z + b0.z);
    o0.w = f2bits((v0.w-mean)*rstd*g0.w + b0.w);
    o1.x = f2bits((v1.x-mean)*rstd*g1.x + b1.x);
    o1.y = f2bits((v1.y-mean)*rstd*g1.y + b1.y);
    o1.z = f2bits((v1.z-mean)*rstd*g1.z + b1.z);
    o1.w = f2bits((v1.w-mean)*rstd*g1.w + b1.w);
    ushort4* yr = (ushort4*)(y + (size_t)row * DIM);
    yr[lane] = o0; yr[lane+64] = o1;
}

// ---------- mean over P: [b,p,n,d] -> [b,n,d], 4 elems/thread ----------
__global__ void mean_kernel(const u16* __restrict__ L, u16* __restrict__ G)
{
    const int idx = blockIdx.x * 256 + threadIdx.x;   // < 8*256*512/4
    const int b = idx >> 15;
    const int rem = idx & 32767;
    float a0 = 0.f, a1 = 0.f, a2 = 0.f, a3 = 0.f;
#pragma unroll
    for (int p = 0; p < PP; ++p) {
        ushort4 u = *(const ushort4*)(L + ((size_t)b*PP + p)*131072 + rem*4);
        a0 += bits2f(u.x); a1 += bits2f(u.y); a2 += bits2f(u.z); a3 += bits2f(u.w);
    }
    ushort4 o;
    o.x = f2bits(0.25f*a0); o.y = f2bits(0.25f*a1);
    o.z = f2bits(0.25f*a2); o.w = f2bits(0.25f*a3);
    *(ushort4*)(G + (size_t)idx*4) = o;
}

// ---------- s_attn: sigmoid( [xl, xg] . ws + bs ), one wave per row ----------
__global__ __launch_bounds__(256)
void sattn_kernel(const u16* __restrict__ xl, const u16* __restrict__ xg,
                  const float* __restrict__ wsv, const float* __restrict__ bs,
                  float* __restrict__ S)
{
    const int wave = threadIdx.x >> 6, lane = threadIdx.x & 63;
    const int row = blockIdx.x * 4 + wave;
    const int b = row >> 10;
    const int n = row & 255;
    const u16* xlr = xl + (size_t)row * RED;
    const u16* xgr = xg + ((size_t)b*NN + n) * RED;
    float s = bits2f(xlr[lane])    * wsv[lane]
            + bits2f(xlr[lane+64]) * wsv[lane+64]
            + bits2f(xgr[lane])    * wsv[RED+lane]
            + bits2f(xgr[lane+64]) * wsv[RED+64+lane];
#pragma unroll
    for (int off = 32; off; off >>= 1) s += __shfl_xor(s, off);
    if (lane == 0) S[row] = 1.f / (1.f + __expf(-(s + bs[0])));
}

// ---------- fuse: x_new = x_attn_res + mlp_out * c_attn * s_attn (4 elems/thread) ----------
__global__ void fuse_kernel(const float4* __restrict__ xb, const float4* __restrict__ m1,
                            const u16* __restrict__ ca, const float* __restrict__ S,
                            float4* __restrict__ xa)
{
    const int idx = blockIdx.x * 256 + threadIdx.x;   // < XELEMS/4
    const int r = idx >> 7;          // 128 float4-groups per row
    const int dg = idx & 127;
    const int b = r >> 10;
    const int n = r & 255;
    const float s = S[r];
    ushort4 cu = *(const ushort4*)(ca + ((((size_t)b << 8) + n)*DIM) + dg*4);
    float4 xv = xb[idx], mv = m1[idx], o;
    o.x = xv.x + mv.x * bits2f(cu.x) * s;
    o.y = xv.y + mv.y * bits2f(cu.y) * s;
    o.z = xv.z + mv.z * bits2f(cu.z) * s;
    o.w = xv.w + mv.w * bits2f(cu.w) * s;
    xa[idx] = o;
}

// ---------- host launch ----------
extern "C" void kernel_launch(void* const* d_in, const int* in_sizes, int n_in,
                              void* d_out, int out_size, void* d_ws, size_t ws_size,
                              hipStream_t stream)
{
    const float* x_in  = (const float*)d_in[0];
    const float* ln1_g = (const float*)d_in[1];
    const float* ln1_b = (const float*)d_in[2];
    const float* w_qkv = (const float*)d_in[3];
    const float* w_o   = (const float*)d_in[4];
    const float* b_o   = (const float*)d_in[5];
    const float* ln2_g = (const float*)d_in[6];
    const float* ln2_b = (const float*)d_in[7];
    const float* w1    = (const float*)d_in[8];
    const float* b1    = (const float*)d_in[9];
    const float* w2    = (const float*)d_in[10];
    const float* b2    = (const float*)d_in[11];
    const float* bn_g  = (const float*)d_in[12];
    const float* bn_b  = (const float*)d_in[13];
    const float* wg    = (const float*)d_in[14];
    const float* bg    = (const float*)d_in[15];
    const float* wl    = (const float*)d_in[16];
    const float* bl    = (const float*)d_in[17];
    const float* wc    = (const float*)d_in[18];
    const float* bc    = (const float*)d_in[19];
    const float* wsw   = (const float*)d_in[20];
    const float* bsb   = (const float*)d_in[21];

    char* ws = (char*)d_ws;
    auto alloc = [&](size_t bytes) {
        char* p = ws;
        ws += (bytes + 255) & ~(size_t)255;
        return p;
    };
    float* XA = (float*)alloc(XELEMS * 4);
    float* XB = (float*)alloc(XELEMS * 4);
    float* M1 = (float*)alloc(XELEMS * 4);
    u16*   L  = (u16*)  alloc(XELEMS * 2);
    u16*   Q  = (u16*)  alloc((size_t)ROWS * 3*DIM * 2);
    u16*   H  = (u16*)  alloc((size_t)ROWS * MLPD * 2);
    u16*   G  = (u16*)  alloc((size_t)BB*NN*DIM * 2);
    u16*   G2 = (u16*)  alloc((size_t)BB*NN*RED * 2);
    u16*   XL = (u16*)  alloc((size_t)ROWS*RED * 2);
    u16*   CA = (u16*)  alloc((size_t)BB*NN*DIM * 2);
    float* S  = (float*)alloc((size_t)ROWS * 4);
    // all-layer transposed bf16 weights
    u16* WTqkv = (u16*)alloc((size_t)DEPTH*DIM*3*DIM * 2);
    u16* WTo   = (u16*)alloc((size_t)DEPTH*DIM*DIM * 2);
    u16* WT1   = (u16*)alloc((size_t)DEPTH*DIM*MLPD * 2);
    u16* WT2   = (u16*)alloc((size_t)DEPTH*MLPD*DIM * 2);
    u16* WTl   = (u16*)alloc((size_t)DEPTH*DIM*RED * 2);
    u16* WTg   = (u16*)alloc((size_t)DEPTH*DIM*RED * 2);
    u16* WTc   = (u16*)alloc((size_t)DEPTH*RED*DIM * 2);

    // ---- all weight transposes upfront, batched over depth ----
    wtrans_all<<<dim3(48,16,DEPTH), 256, 0, stream>>>(w_qkv, WTqkv, DIM, 3*DIM);
    wtrans_all<<<dim3(16,16,DEPTH), 256, 0, stream>>>(w_o,   WTo,   DIM, DIM);
    wtrans_all<<<dim3(64,16,DEPTH), 256, 0, stream>>>(w1,    WT1,   DIM, MLPD);
    wtrans_all<<<dim3(16,64,DEPTH), 256, 0, stream>>>(w2,    WT2,   MLPD, DIM);
    wtrans_all<<<dim3(4,16,DEPTH),  256, 0, stream>>>(wl,    WTl,   DIM, RED);
    wtrans_all<<<dim3(4,16,DEPTH),  256, 0, stream>>>(wg,    WTg,   DIM, RED);
    wtrans_all<<<dim3(16,4,DEPTH),  256, 0, stream>>>(wc,    WTc,   RED, DIM);

    for (int l = 0; l < DEPTH; ++l) {
        const float* Xres = l ? (const float*)XA : x_in;   // layer-0 reads input directly
        // ---- attention block ----
        ln_kernel<<<ROWS/4, 256, 0, stream>>>(Xres, ln1_g + l*DIM, ln1_b + l*DIM, L, ROWS);
        gemm_db<128,128,32,2,2><<<64*12, 256, 0, stream>>>(
            L, WTqkv + (size_t)l*DIM*3*DIM, nullptr, nullptr, Q, ROWS, 3*DIM, DIM, 0, 0);
        attn_mfma<<<BB*PP*HEADS, 256, 0, stream>>>(Q, L);
        gemm_db<64,128,64,2,2><<<128*4, 256, 0, stream>>>(
            L, WTo + (size_t)l*DIM*DIM, b_o + l*DIM, Xres, XB, ROWS, DIM, DIM, 0, 1);

        // ---- MLP ----
        ln_kernel<<<ROWS/4, 256, 0, stream>>>(XB, ln2_g + l*DIM, ln2_b + l*DIM, Q, ROWS);
        gemm_db<128,128,32,2,2><<<64*16, 256, 0, stream>>>(
            Q, WT1 + (size_t)l*DIM*MLPD, b1 + l*MLPD, nullptr, H, ROWS, MLPD, DIM, 1, 0);
        gemm_db<64,128,64,2,2><<<128*4, 256, 0, stream>>>(
            H, WT2 + (size_t)l*MLPD*DIM, b2 + l*DIM, nullptr, M1, ROWS, DIM, MLPD, 0, 1);

        // ---- BiAttn ----
        ln_kernel<<<ROWS/4, 256, 0, stream>>>(M1, bn_g + l*DIM, bn_b + l*DIM, L, ROWS);
        mean_kernel<<<(BB*NN*DIM)/1024, 256, 0, stream>>>(L, G);
        gemm_db<64,64,64,2,2><<<32*2, 256, 0, stream>>>(
            G, WTg + (size_t)l*DIM*RED, bg + l*RED, nullptr, G2, BB*NN, RED, DIM, 1, 0);
        gemm_db<64,64,64,2,2><<<128*2, 256, 0, stream>>>(
            L, WTl + (size_t)l*DIM*RED, bl + l*RED, nullptr, XL, ROWS, RED, DIM, 1, 0);
        gemm_db<64,64,64,2,2><<<32*8, 256, 0, stream>>>(
            G2, WTc + (size_t)l*RED*DIM, bc + l*DIM, nullptr, CA, BB*NN, DIM, RED, 2, 0);
        sattn_kernel<<<ROWS/4, 256, 0, stream>>>(XL, G2, wsw + (size_t)l*2*RED, bsb + l, S);
        // last layer writes the fp32 output buffer directly (drops final copy)
        fuse_kernel<<<XELEMS/1024, 256, 0, stream>>>((const float4*)XB, (const float4*)M1,
                                                     CA, S,
                                                     (l == DEPTH-1) ? (float4*)d_out
                                                                    : (float4*)XA);
    }
}

// Round 6
// 958.830 us; speedup vs baseline: 1.3461x; 1.0710x over previous
//
#include <hip/hip_runtime.h>
#include <hip/hip_bf16.h>
#include <math.h>

typedef __hip_bfloat16 bf16;
typedef unsigned short u16;
typedef __bf16 bf16x8 __attribute__((ext_vector_type(8)));
typedef float f32x4 __attribute__((ext_vector_type(4)));

// ---------- helpers ----------
__device__ __forceinline__ float b2f(bf16 v) { return __bfloat162float(v); }
__device__ __forceinline__ bf16 f2b(float v) { return __float2bfloat16(v); }
__device__ __forceinline__ float bits2f(unsigned int u) {
    union { unsigned int i; float f; } w; w.i = u << 16; return w.f;
}
__device__ __forceinline__ u16 f2bits(float v) {
    union { bf16 h; u16 u; } w; w.h = __float2bfloat16(v); return w.u;
}
__device__ __forceinline__ void async16(void* lds, const void* g) {
    __builtin_amdgcn_global_load_lds(
        (const __attribute__((address_space(1))) unsigned int*)g,
        (__attribute__((address_space(3))) unsigned int*)lds, 16, 0, 0);
}

#define DEPTH 4
#define HEADS 8
#define DHEAD 64
#define DIM 512
#define MLPD 2048
#define RED 128
#define BB 8
#define PP 4
#define NN 256
#define ROWS (BB*PP*NN)          // 8192 tokens
#define XELEMS ((size_t)ROWS*DIM) // 4194304

// ---------- batched weight transpose+cast: W fp32 [D][K][N] -> WT bf16 [D][N][K] ----------
__global__ __launch_bounds__(256)
void wtrans_all(const float* __restrict__ W, u16* __restrict__ WT, int K, int N)
{
    __shared__ float T[32][33];
    const int l = blockIdx.z;
    W  += (size_t)l * K * N;
    WT += (size_t)l * N * K;
    const int tx = threadIdx.x & 31, ty = threadIdx.x >> 5; // ty 0..7
    const int n0 = blockIdx.x * 32, k0 = blockIdx.y * 32;
#pragma unroll
    for (int r = 0; r < 4; ++r)
        T[ty + r*8][tx] = W[(size_t)(k0 + ty + r*8) * N + n0 + tx];
    __syncthreads();
#pragma unroll
    for (int r = 0; r < 4; ++r)
        WT[(size_t)(n0 + ty + r*8) * K + k0 + tx] = f2bits(T[tx][ty + r*8]);
}

// ---------- double-buffered MFMA GEMM (2-phase): C = act(A @ WT^T + bias) [+res]
// Round-0 verified geometry: 2-D grid (x = M-tile, y = N-tile), no swizzle.
template<int BM, int BN, int BK, int WROWS, int WCOLS>
__global__ __launch_bounds__(256)
void gemm_db(const u16* __restrict__ A, const u16* __restrict__ WT,
             const float* __restrict__ bias, const float* __restrict__ res,
             void* __restrict__ Cv, int M, int N, int K, int act, int outf32)
{
    constexpr int KG  = BK/8;        // 16B k-groups per row
    constexpr int RPC = 512/BK;      // rows per 1KB staging chunk
    constexpr int NCA = BM*BK/512;   // A chunks
    constexpr int NCB = BN*BK/512;   // B chunks
    constexpr int CPT = (NCA+NCB)/4; // chunks per wave
    constexpr int WM = BM/WROWS, WN = BN/WCOLS;
    constexpr int AM = WM/16, AN = WN/16, KB = BK/32;

    __shared__ u16 As[2][BM*BK];
    __shared__ u16 Bs[2][BN*BK];
    const int tid = threadIdx.x, wave = tid >> 6, lane = tid & 63;
    const int bm = blockIdx.x * BM;
    const int bn = blockIdx.y * BN;
    const int wm = (wave / WCOLS) * WM, wn = (wave % WCOLS) * WN;
    const int lr = lane & 15, quad = lane >> 4;

    const int rowc = lane / KG;
    const int kgs  = ((lane & (KG-1)) ^ (KG == 4 ? ((rowc >> 1) & 3) : (rowc & 7))) * 8;

    auto stage = [&](int buf, int k0) {
#pragma unroll
        for (int t = 0; t < CPT; ++t) {
            const int c = wave*CPT + t;
            if (c < NCA)
                async16(&As[buf][c*512], A  + (size_t)(bm + c*RPC + rowc) * K + k0 + kgs);
            else
                async16(&Bs[buf][(c-NCA)*512], WT + (size_t)(bn + (c-NCA)*RPC + rowc) * K + k0 + kgs);
        }
    };

    f32x4 acc[AM][AN] = {};

    stage(0, 0);
    __syncthreads();

    const int NK = K / BK;
    for (int ki = 0; ki < NK; ++ki) {
        const int cur = ki & 1;
        if (ki + 1 < NK) stage(cur ^ 1, (ki + 1) * BK);

        bf16x8 af[AM][KB], bv[AN][KB];
#pragma unroll
        for (int i = 0; i < AM; ++i) {
            const int rA = wm + i*16 + lr;
            const int sw = (KG == 4 ? (((rA & 15) >> 1) & 3) : (rA & 7));
#pragma unroll
            for (int kb = 0; kb < KB; ++kb)
                af[i][kb] = *(const bf16x8*)(As[cur] + rA*BK + (((kb*4 + quad) ^ sw) * 8));
        }
#pragma unroll
        for (int j = 0; j < AN; ++j) {
            const int rB = wn + j*16 + lr;
            const int sw = (KG == 4 ? (((rB & 15) >> 1) & 3) : (rB & 7));
#pragma unroll
            for (int kb = 0; kb < KB; ++kb)
                bv[j][kb] = *(const bf16x8*)(Bs[cur] + rB*BK + (((kb*4 + quad) ^ sw) * 8));
        }
#pragma unroll
        for (int i = 0; i < AM; ++i)
#pragma unroll
            for (int j = 0; j < AN; ++j)
#pragma unroll
                for (int kb = 0; kb < KB; ++kb)
                    acc[i][j] = __builtin_amdgcn_mfma_f32_16x16x32_bf16(
                        af[i][kb], bv[j][kb], acc[i][j], 0, 0, 0);
        __syncthreads();
    }

#pragma unroll
    for (int i = 0; i < AM; ++i) {
        const int rowb = bm + wm + i*16 + quad*4;
#pragma unroll
        for (int j = 0; j < AN; ++j) {
            const int col = bn + wn + j*16 + lr;
            const float bvs = bias ? bias[col] : 0.f;
#pragma unroll
            for (int r = 0; r < 4; ++r) {
                float v = acc[i][j][r] + bvs;
                if (act == 1) v = 0.5f * v * (1.0f + erff(v * 0.70710678118f));
                else if (act == 2) v = 1.0f / (1.0f + __expf(-v));
                const size_t idx = (size_t)(rowb + r) * N + col;
                if (res) v += res[idx];
                if (outf32) ((float*)Cv)[idx] = v;
                else        ((u16*)Cv)[idx] = f2bits(v);
            }
        }
    }
}

// ---------- MFMA flash attention: one block per (b,p,h), wave = 64 query rows ----------
__global__ __launch_bounds__(256)
void attn_mfma(const u16* __restrict__ qkv, u16* __restrict__ out)
{
    __shared__ u16 Kt[64*72];
    __shared__ u16 Vt[64*72];
    __shared__ u16 Pw[4][64*72];
    const int tid = threadIdx.x;
    const int wave = tid >> 6, lane = tid & 63;
    const int lr = lane & 15, quad = lane >> 4;
    const int bp = blockIdx.x >> 3, h = blockIdx.x & 7;
    const u16* base = qkv + (size_t)bp * NN * (3*DIM);
    const int qo = h*DHEAD, ko = DIM + h*DHEAD, vo = 2*DIM + h*DHEAD;
    const int m0 = wave * 64;

    bf16x8 qf[4][2];
#pragma unroll
    for (int i = 0; i < 4; ++i)
#pragma unroll
        for (int kb = 0; kb < 2; ++kb)
            qf[i][kb] = *(const bf16x8*)(base + (size_t)(m0 + i*16 + lr)*(3*DIM)
                                         + qo + kb*32 + quad*8);

    f32x4 o[4][4] = {};
    float mrow[4][4], lrow[4][4];
#pragma unroll
    for (int i = 0; i < 4; ++i)
#pragma unroll
        for (int r = 0; r < 4; ++r) { mrow[i][r] = -1e30f; lrow[i][r] = 0.f; }

    const int sr = tid >> 3, sc = tid & 7;

    for (int t = 0; t < 4; ++t) {
        __syncthreads();
#pragma unroll
        for (int half = 0; half < 2; ++half) {
            const int key = half*32 + sr;
            const u16* krow = base + (size_t)(t*64 + key)*(3*DIM);
            uint4 kv = *(const uint4*)(krow + ko + sc*8);
            *(uint4*)(Kt + key*72 + sc*8) = kv;
            uint4 vv = *(const uint4*)(krow + vo + sc*8);
            const int d0 = sc*8;
            Vt[(d0+0)*72 + key] = (u16)(vv.x & 0xffffu);
            Vt[(d0+1)*72 + key] = (u16)(vv.x >> 16);
            Vt[(d0+2)*72 + key] = (u16)(vv.y & 0xffffu);
            Vt[(d0+3)*72 + key] = (u16)(vv.y >> 16);
            Vt[(d0+4)*72 + key] = (u16)(vv.z & 0xffffu);
            Vt[(d0+5)*72 + key] = (u16)(vv.z >> 16);
            Vt[(d0+6)*72 + key] = (u16)(vv.w & 0xffffu);
            Vt[(d0+7)*72 + key] = (u16)(vv.w >> 16);
        }
        __syncthreads();

        f32x4 s[4][4] = {};
        bf16x8 kf[4][2];
#pragma unroll
        for (int j = 0; j < 4; ++j)
#pragma unroll
            for (int kb = 0; kb < 2; ++kb)
                kf[j][kb] = *(const bf16x8*)(Kt + (j*16 + lr)*72 + kb*32 + quad*8);
#pragma unroll
        for (int i = 0; i < 4; ++i)
#pragma unroll
            for (int j = 0; j < 4; ++j)
#pragma unroll
                for (int kb = 0; kb < 2; ++kb)
                    s[i][j] = __builtin_amdgcn_mfma_f32_16x16x32_bf16(
                        qf[i][kb], kf[j][kb], s[i][j], 0, 0, 0);

        float alpha[4][4];
#pragma unroll
        for (int i = 0; i < 4; ++i)
#pragma unroll
            for (int r = 0; r < 4; ++r) {
#pragma unroll
                for (int j = 0; j < 4; ++j) s[i][j][r] *= 0.125f;
                float mt = fmaxf(fmaxf(s[i][0][r], s[i][1][r]),
                                 fmaxf(s[i][2][r], s[i][3][r]));
#pragma unroll
                for (int off = 1; off <= 8; off <<= 1) mt = fmaxf(mt, __shfl_xor(mt, off));
                const float mn = fmaxf(mrow[i][r], mt);
                alpha[i][r] = __expf(mrow[i][r] - mn);
                mrow[i][r] = mn;
                float ssum = 0.f;
#pragma unroll
                for (int j = 0; j < 4; ++j) {
                    const float p = __expf(s[i][j][r] - mn);
                    s[i][j][r] = p; ssum += p;
                }
#pragma unroll
                for (int off = 1; off <= 8; off <<= 1) ssum += __shfl_xor(ssum, off);
                lrow[i][r] = lrow[i][r]*alpha[i][r] + ssum;
            }

#pragma unroll
        for (int i = 0; i < 4; ++i)
#pragma unroll
            for (int j = 0; j < 4; ++j)
#pragma unroll
                for (int r = 0; r < 4; ++r)
                    Pw[wave][(i*16 + quad*4 + r)*72 + j*16 + lr] = f2bits(s[i][j][r]);
        __syncthreads();

#pragma unroll
        for (int i = 0; i < 4; ++i)
#pragma unroll
            for (int jd = 0; jd < 4; ++jd)
#pragma unroll
                for (int r = 0; r < 4; ++r)
                    o[i][jd][r] *= alpha[i][r];

        bf16x8 af[4][2], bv[4][2];
#pragma unroll
        for (int i = 0; i < 4; ++i)
#pragma unroll
            for (int kb = 0; kb < 2; ++kb)
                af[i][kb] = *(const bf16x8*)(Pw[wave] + (i*16 + lr)*72 + kb*32 + quad*8);
#pragma unroll
        for (int jd = 0; jd < 4; ++jd)
#pragma unroll
            for (int kb = 0; kb < 2; ++kb)
                bv[jd][kb] = *(const bf16x8*)(Vt + (jd*16 + lr)*72 + kb*32 + quad*8);
#pragma unroll
        for (int i = 0; i < 4; ++i)
#pragma unroll
            for (int jd = 0; jd < 4; ++jd)
#pragma unroll
                for (int kb = 0; kb < 2; ++kb)
                    o[i][jd] = __builtin_amdgcn_mfma_f32_16x16x32_bf16(
                        af[i][kb], bv[jd][kb], o[i][jd], 0, 0, 0);
    }

#pragma unroll
    for (int i = 0; i < 4; ++i)
#pragma unroll
        for (int r = 0; r < 4; ++r) {
            const float inv = 1.0f / lrow[i][r];
            const size_t rowg = (size_t)bp*NN + m0 + i*16 + quad*4 + r;
#pragma unroll
            for (int jd = 0; jd < 4; ++jd)
                out[rowg*DIM + h*DHEAD + jd*16 + lr] = f2bits(o[i][jd][r] * inv);
        }
}

// ---------- LayerNorm over DIM=512, fp32 in, bf16 out; one wave per row; float4 ----------
__global__ __launch_bounds__(256)
void ln_kernel(const float* __restrict__ x, const float* __restrict__ g,
               const float* __restrict__ b, u16* __restrict__ y, int rows)
{
    const int wave = threadIdx.x >> 6, lane = threadIdx.x & 63;
    const int row = blockIdx.x * 4 + wave;
    if (row >= rows) return;
    const float4* xr = (const float4*)(x + (size_t)row * DIM);
    float4 v0 = xr[lane], v1 = xr[lane + 64];
    float s  = v0.x+v0.y+v0.z+v0.w + v1.x+v1.y+v1.z+v1.w;
    float s2 = v0.x*v0.x+v0.y*v0.y+v0.z*v0.z+v0.w*v0.w
             + v1.x*v1.x+v1.y*v1.y+v1.z*v1.z+v1.w*v1.w;
#pragma unroll
    for (int off = 32; off; off >>= 1) { s += __shfl_xor(s, off); s2 += __shfl_xor(s2, off); }
    const float mean = s * (1.f/512.f);
    const float var  = s2 * (1.f/512.f) - mean*mean;
    const float rstd = rsqrtf(var + 1e-5f);
    const float4* gp = (const float4*)g; const float4* bp = (const float4*)b;
    float4 g0 = gp[lane], g1 = gp[lane+64], b0 = bp[lane], b1 = bp[lane+64];
    ushort4 o0, o1;
    o0.x = f2bits((v0.x-mean)*rstd*g0.x + b0.x);
    o0.y = f2bits((v0.y-mean)*rstd*g0.y + b0.y);
    o0.z = f2bits((v0.z-mean)*rstd*g0.z + b0.z);
    o0.w = f2bits((v0.w-mean)*rstd*g0.w + b0.w);
    o1.x = f2bits((v1.x-mean)*rstd*g1.x + b1.x);
    o1.y = f2bits((v1.y-mean)*rstd*g1.y + b1.y);
    o1.z = f2bits((v1.z-mean)*rstd*g1.z + b1.z);
    o1.w = f2bits((v1.w-mean)*rstd*g1.w + b1.w);
    ushort4* yr = (ushort4*)(y + (size_t)row * DIM);
    yr[lane] = o0; yr[lane+64] = o1;
}

// ---------- fused BiAttn LN + mean over P: block=(b,n), wave p=0..3 ----------
// Wave p LayerNorms row (b,p,n) -> L; block reduces over p -> G[b,n,:] (bf16).
__global__ __launch_bounds__(256)
void lnmean_kernel(const float* __restrict__ x, const float* __restrict__ g,
                   const float* __restrict__ b, u16* __restrict__ y,
                   u16* __restrict__ G)
{
    __shared__ float T[4][512];
    const int wave = threadIdx.x >> 6, lane = threadIdx.x & 63;
    const int bb = blockIdx.x >> 8, n = blockIdx.x & 255;
    const int row = (bb*PP + wave)*NN + n;
    const float4* xr = (const float4*)(x + (size_t)row * DIM);
    float4 v0 = xr[lane], v1 = xr[lane + 64];
    float s  = v0.x+v0.y+v0.z+v0.w + v1.x+v1.y+v1.z+v1.w;
    float s2 = v0.x*v0.x+v0.y*v0.y+v0.z*v0.z+v0.w*v0.w
             + v1.x*v1.x+v1.y*v1.y+v1.z*v1.z+v1.w*v1.w;
#pragma unroll
    for (int off = 32; off; off >>= 1) { s += __shfl_xor(s, off); s2 += __shfl_xor(s2, off); }
    const float mean = s * (1.f/512.f);
    const float var  = s2 * (1.f/512.f) - mean*mean;
    const float rstd = rsqrtf(var + 1e-5f);
    const float4* gp = (const float4*)g; const float4* bp = (const float4*)b;
    float4 g0 = gp[lane], g1 = gp[lane+64], b0 = bp[lane], b1 = bp[lane+64];
    float4 y0, y1;
    y0.x = (v0.x-mean)*rstd*g0.x + b0.x;
    y0.y = (v0.y-mean)*rstd*g0.y + b0.y;
    y0.z = (v0.z-mean)*rstd*g0.z + b0.z;
    y0.w = (v0.w-mean)*rstd*g0.w + b0.w;
    y1.x = (v1.x-mean)*rstd*g1.x + b1.x;
    y1.y = (v1.y-mean)*rstd*g1.y + b1.y;
    y1.z = (v1.z-mean)*rstd*g1.z + b1.z;
    y1.w = (v1.w-mean)*rstd*g1.w + b1.w;
    ushort4 o0, o1;
    o0.x = f2bits(y0.x); o0.y = f2bits(y0.y); o0.z = f2bits(y0.z); o0.w = f2bits(y0.w);
    o1.x = f2bits(y1.x); o1.y = f2bits(y1.y); o1.z = f2bits(y1.z); o1.w = f2bits(y1.w);
    ushort4* yr = (ushort4*)(y + (size_t)row * DIM);
    yr[lane] = o0; yr[lane+64] = o1;
    *(float4*)&T[wave][lane*4]       = y0;
    *(float4*)&T[wave][256 + lane*4] = y1;
    __syncthreads();
    const int d0 = threadIdx.x;   // 0..255, handles d0 and d0+256
    const float m0 = (T[0][d0]     + T[1][d0]     + T[2][d0]     + T[3][d0])     * 0.25f;
    const float m1 = (T[0][d0+256] + T[1][d0+256] + T[2][d0+256] + T[3][d0+256]) * 0.25f;
    u16* gr = G + ((size_t)bb*NN + n)*DIM;
    gr[d0]       = f2bits(m0);
    gr[d0 + 256] = f2bits(m1);
}

// ---------- fused s_attn + fuse: wave per row; s in-register, then update ----------
__global__ __launch_bounds__(256)
void fuse2_kernel(const float4* __restrict__ xb, const float4* __restrict__ m1,
                  const u16* __restrict__ ca, const u16* __restrict__ xl,
                  const u16* __restrict__ xg, const float* __restrict__ wsv,
                  const float* __restrict__ bs, float4* __restrict__ xa)
{
    const int wave = threadIdx.x >> 6, lane = threadIdx.x & 63;
    const int row = blockIdx.x * 4 + wave;
    const int b = row >> 10, n = row & 255;
    const u16* xlr = xl + (size_t)row * RED;
    const u16* xgr = xg + ((size_t)b*NN + n) * RED;
    float s = bits2f(xlr[lane])    * wsv[lane]
            + bits2f(xlr[lane+64]) * wsv[lane+64]
            + bits2f(xgr[lane])    * wsv[RED+lane]
            + bits2f(xgr[lane+64]) * wsv[RED+64+lane];
#pragma unroll
    for (int off = 32; off; off >>= 1) s += __shfl_xor(s, off);
    s = 1.f / (1.f + __expf(-(s + bs[0])));
    const u16* car = ca + ((((size_t)b << 8) + n)*DIM);
#pragma unroll
    for (int t = 0; t < 2; ++t) {
        const int dg = lane + t*64;
        const size_t idx = (size_t)row*128 + dg;
        ushort4 cu = *(const ushort4*)(car + dg*4);
        float4 xv = xb[idx], mv = m1[idx], o;
        o.x = xv.x + mv.x * bits2f(cu.x) * s;
        o.y = xv.y + mv.y * bits2f(cu.y) * s;
        o.z = xv.z + mv.z * bits2f(cu.z) * s;
        o.w = xv.w + mv.w * bits2f(cu.w) * s;
        xa[idx] = o;
    }
}

// ---------- host launch ----------
extern "C" void kernel_launch(void* const* d_in, const int* in_sizes, int n_in,
                              void* d_out, int out_size, void* d_ws, size_t ws_size,
                              hipStream_t stream)
{
    const float* x_in  = (const float*)d_in[0];
    const float* ln1_g = (const float*)d_in[1];
    const float* ln1_b = (const float*)d_in[2];
    const float* w_qkv = (const float*)d_in[3];
    const float* w_o   = (const float*)d_in[4];
    const float* b_o   = (const float*)d_in[5];
    const float* ln2_g = (const float*)d_in[6];
    const float* ln2_b = (const float*)d_in[7];
    const float* w1    = (const float*)d_in[8];
    const float* b1    = (const float*)d_in[9];
    const float* w2    = (const float*)d_in[10];
    const float* b2    = (const float*)d_in[11];
    const float* bn_g  = (const float*)d_in[12];
    const float* bn_b  = (const float*)d_in[13];
    const float* wg    = (const float*)d_in[14];
    const float* bg    = (const float*)d_in[15];
    const float* wl    = (const float*)d_in[16];
    const float* bl    = (const float*)d_in[17];
    const float* wc    = (const float*)d_in[18];
    const float* bc    = (const float*)d_in[19];
    const float* wsw   = (const float*)d_in[20];
    const float* bsb   = (const float*)d_in[21];

    char* ws = (char*)d_ws;
    auto alloc = [&](size_t bytes) {
        char* p = ws;
        ws += (bytes + 255) & ~(size_t)255;
        return p;
    };
    float* XA = (float*)alloc(XELEMS * 4);
    float* XB = (float*)alloc(XELEMS * 4);
    float* M1 = (float*)alloc(XELEMS * 4);
    u16*   L  = (u16*)  alloc(XELEMS * 2);
    u16*   Q  = (u16*)  alloc((size_t)ROWS * 3*DIM * 2);
    u16*   H  = (u16*)  alloc((size_t)ROWS * MLPD * 2);
    u16*   G  = (u16*)  alloc((size_t)BB*NN*DIM * 2);
    u16*   G2 = (u16*)  alloc((size_t)BB*NN*RED * 2);
    u16*   XL = (u16*)  alloc((size_t)ROWS*RED * 2);
    u16*   CA = (u16*)  alloc((size_t)BB*NN*DIM * 2);
    // all-layer transposed bf16 weights
    u16* WTqkv = (u16*)alloc((size_t)DEPTH*DIM*3*DIM * 2);
    u16* WTo   = (u16*)alloc((size_t)DEPTH*DIM*DIM * 2);
    u16* WT1   = (u16*)alloc((size_t)DEPTH*DIM*MLPD * 2);
    u16* WT2   = (u16*)alloc((size_t)DEPTH*MLPD*DIM * 2);
    u16* WTl   = (u16*)alloc((size_t)DEPTH*DIM*RED * 2);
    u16* WTg   = (u16*)alloc((size_t)DEPTH*DIM*RED * 2);
    u16* WTc   = (u16*)alloc((size_t)DEPTH*RED*DIM * 2);

    // ---- all weight transposes upfront, batched over depth ----
    wtrans_all<<<dim3(48,16,DEPTH), 256, 0, stream>>>(w_qkv, WTqkv, DIM, 3*DIM);
    wtrans_all<<<dim3(16,16,DEPTH), 256, 0, stream>>>(w_o,   WTo,   DIM, DIM);
    wtrans_all<<<dim3(64,16,DEPTH), 256, 0, stream>>>(w1,    WT1,   DIM, MLPD);
    wtrans_all<<<dim3(16,64,DEPTH), 256, 0, stream>>>(w2,    WT2,   MLPD, DIM);
    wtrans_all<<<dim3(4,16,DEPTH),  256, 0, stream>>>(wl,    WTl,   DIM, RED);
    wtrans_all<<<dim3(4,16,DEPTH),  256, 0, stream>>>(wg,    WTg,   DIM, RED);
    wtrans_all<<<dim3(16,4,DEPTH),  256, 0, stream>>>(wc,    WTc,   RED, DIM);

    for (int l = 0; l < DEPTH; ++l) {
        const float* Xres = l ? (const float*)XA : x_in;   // layer-0 reads input directly
        // ---- attention block ----
        ln_kernel<<<ROWS/4, 256, 0, stream>>>(Xres, ln1_g + l*DIM, ln1_b + l*DIM, L, ROWS);
        gemm_db<64,128,64,2,2><<<dim3(128,12), 256, 0, stream>>>(
            L, WTqkv + (size_t)l*DIM*3*DIM, nullptr, nullptr, Q, ROWS, 3*DIM, DIM, 0, 0);
        attn_mfma<<<BB*PP*HEADS, 256, 0, stream>>>(Q, L);
        gemm_db<64,128,64,2,2><<<dim3(128,4), 256, 0, stream>>>(
            L, WTo + (size_t)l*DIM*DIM, b_o + l*DIM, Xres, XB, ROWS, DIM, DIM, 0, 1);

        // ---- MLP ----
        ln_kernel<<<ROWS/4, 256, 0, stream>>>(XB, ln2_g + l*DIM, ln2_b + l*DIM, Q, ROWS);
        gemm_db<64,128,64,2,2><<<dim3(128,16), 256, 0, stream>>>(
            Q, WT1 + (size_t)l*DIM*MLPD, b1 + l*MLPD, nullptr, H, ROWS, MLPD, DIM, 1, 0);
        gemm_db<64,128,64,2,2><<<dim3(128,4), 256, 0, stream>>>(
            H, WT2 + (size_t)l*MLPD*DIM, b2 + l*DIM, nullptr, M1, ROWS, DIM, MLPD, 0, 1);

        // ---- BiAttn ----
        lnmean_kernel<<<BB*NN, 256, 0, stream>>>(M1, bn_g + l*DIM, bn_b + l*DIM, L, G);
        gemm_db<64,64,64,2,2><<<dim3(32,2), 256, 0, stream>>>(
            G, WTg + (size_t)l*DIM*RED, bg + l*RED, nullptr, G2, BB*NN, RED, DIM, 1, 0);
        gemm_db<64,64,64,2,2><<<dim3(128,2), 256, 0, stream>>>(
            L, WTl + (size_t)l*DIM*RED, bl + l*RED, nullptr, XL, ROWS, RED, DIM, 1, 0);
        gemm_db<64,64,64,2,2><<<dim3(32,8), 256, 0, stream>>>(
            G2, WTc + (size_t)l*RED*DIM, bc + l*DIM, nullptr, CA, BB*NN, DIM, RED, 2, 0);
        // fused s_attn + gating + residual; last layer writes d_out directly
        fuse2_kernel<<<ROWS/4, 256, 0, stream>>>((const float4*)XB, (const float4*)M1,
                                                 CA, XL, G2, wsw + (size_t)l*2*RED, bsb + l,
                                                 (l == DEPTH-1) ? (float4*)d_out
                                                                : (float4*)XA);
    }
}

// Round 7
// 945.592 us; speedup vs baseline: 1.3649x; 1.0140x over previous
//
#include <hip/hip_runtime.h>
#include <hip/hip_bf16.h>
#include <math.h>

typedef __hip_bfloat16 bf16;
typedef unsigned short u16;
typedef __bf16 bf16x8 __attribute__((ext_vector_type(8)));
typedef float f32x4 __attribute__((ext_vector_type(4)));

// ---------- helpers ----------
__device__ __forceinline__ float b2f(bf16 v) { return __bfloat162float(v); }
__device__ __forceinline__ bf16 f2b(float v) { return __float2bfloat16(v); }
__device__ __forceinline__ float bits2f(unsigned int u) {
    union { unsigned int i; float f; } w; w.i = u << 16; return w.f;
}
__device__ __forceinline__ u16 f2bits(float v) {
    union { bf16 h; u16 u; } w; w.h = __float2bfloat16(v); return w.u;
}
__device__ __forceinline__ void async16(void* lds, const void* g) {
    __builtin_amdgcn_global_load_lds(
        (const __attribute__((address_space(1))) unsigned int*)g,
        (__attribute__((address_space(3))) unsigned int*)lds, 16, 0, 0);
}

#define DEPTH 4
#define HEADS 8
#define DHEAD 64
#define DIM 512
#define MLPD 2048
#define RED 128
#define BB 8
#define PP 4
#define NN 256
#define ROWS (BB*PP*NN)          // 8192 tokens
#define XELEMS ((size_t)ROWS*DIM) // 4194304

// ---------- batched weight transpose+cast: W fp32 [D][K][N] -> WT bf16 [D][N][K] ----------
__global__ __launch_bounds__(256)
void wtrans_all(const float* __restrict__ W, u16* __restrict__ WT, int K, int N)
{
    __shared__ float T[32][33];
    const int l = blockIdx.z;
    W  += (size_t)l * K * N;
    WT += (size_t)l * N * K;
    const int tx = threadIdx.x & 31, ty = threadIdx.x >> 5; // ty 0..7
    const int n0 = blockIdx.x * 32, k0 = blockIdx.y * 32;
#pragma unroll
    for (int r = 0; r < 4; ++r)
        T[ty + r*8][tx] = W[(size_t)(k0 + ty + r*8) * N + n0 + tx];
    __syncthreads();
#pragma unroll
    for (int r = 0; r < 4; ++r)
        WT[(size_t)(n0 + ty + r*8) * K + k0 + tx] = f2bits(T[tx][ty + r*8]);
}

// ---------- double-buffered MFMA GEMM (2-phase): C = act(A @ WT^T + bias) [+res]
template<int BM, int BN, int BK, int WROWS, int WCOLS>
__global__ __launch_bounds__(256)
void gemm_db(const u16* __restrict__ A, const u16* __restrict__ WT,
             const float* __restrict__ bias, const float* __restrict__ res,
             void* __restrict__ Cv, int M, int N, int K, int act, int outf32)
{
    constexpr int KG  = BK/8;        // 16B k-groups per row
    constexpr int RPC = 512/BK;      // rows per 1KB staging chunk
    constexpr int NCA = BM*BK/512;   // A chunks
    constexpr int NCB = BN*BK/512;   // B chunks
    constexpr int CPT = (NCA+NCB)/4; // chunks per wave
    constexpr int WM = BM/WROWS, WN = BN/WCOLS;
    constexpr int AM = WM/16, AN = WN/16, KB = BK/32;

    __shared__ u16 As[2][BM*BK];
    __shared__ u16 Bs[2][BN*BK];
    const int tid = threadIdx.x, wave = tid >> 6, lane = tid & 63;
    const int bm = blockIdx.x * BM;
    const int bn = blockIdx.y * BN;
    const int wm = (wave / WCOLS) * WM, wn = (wave % WCOLS) * WN;
    const int lr = lane & 15, quad = lane >> 4;

    const int rowc = lane / KG;
    const int kgs  = ((lane & (KG-1)) ^ (KG == 4 ? ((rowc >> 1) & 3) : (rowc & 7))) * 8;

    auto stage = [&](int buf, int k0) {
#pragma unroll
        for (int t = 0; t < CPT; ++t) {
            const int c = wave*CPT + t;
            if (c < NCA)
                async16(&As[buf][c*512], A  + (size_t)(bm + c*RPC + rowc) * K + k0 + kgs);
            else
                async16(&Bs[buf][(c-NCA)*512], WT + (size_t)(bn + (c-NCA)*RPC + rowc) * K + k0 + kgs);
        }
    };

    f32x4 acc[AM][AN] = {};

    stage(0, 0);
    __syncthreads();

    const int NK = K / BK;
    for (int ki = 0; ki < NK; ++ki) {
        const int cur = ki & 1;
        if (ki + 1 < NK) stage(cur ^ 1, (ki + 1) * BK);

        bf16x8 af[AM][KB], bv[AN][KB];
#pragma unroll
        for (int i = 0; i < AM; ++i) {
            const int rA = wm + i*16 + lr;
            const int sw = (KG == 4 ? (((rA & 15) >> 1) & 3) : (rA & 7));
#pragma unroll
            for (int kb = 0; kb < KB; ++kb)
                af[i][kb] = *(const bf16x8*)(As[cur] + rA*BK + (((kb*4 + quad) ^ sw) * 8));
        }
#pragma unroll
        for (int j = 0; j < AN; ++j) {
            const int rB = wn + j*16 + lr;
            const int sw = (KG == 4 ? (((rB & 15) >> 1) & 3) : (rB & 7));
#pragma unroll
            for (int kb = 0; kb < KB; ++kb)
                bv[j][kb] = *(const bf16x8*)(Bs[cur] + rB*BK + (((kb*4 + quad) ^ sw) * 8));
        }
#pragma unroll
        for (int i = 0; i < AM; ++i)
#pragma unroll
            for (int j = 0; j < AN; ++j)
#pragma unroll
                for (int kb = 0; kb < KB; ++kb)
                    acc[i][j] = __builtin_amdgcn_mfma_f32_16x16x32_bf16(
                        af[i][kb], bv[j][kb], acc[i][j], 0, 0, 0);
        __syncthreads();
    }

#pragma unroll
    for (int i = 0; i < AM; ++i) {
        const int rowb = bm + wm + i*16 + quad*4;
#pragma unroll
        for (int j = 0; j < AN; ++j) {
            const int col = bn + wn + j*16 + lr;
            const float bvs = bias ? bias[col] : 0.f;
#pragma unroll
            for (int r = 0; r < 4; ++r) {
                float v = acc[i][j][r] + bvs;
                if (act == 1) v = 0.5f * v * (1.0f + erff(v * 0.70710678118f));
                else if (act == 2) v = 1.0f / (1.0f + __expf(-v));
                const size_t idx = (size_t)(rowb + r) * N + col;
                if (res) v += res[idx];
                if (outf32) ((float*)Cv)[idx] = v;
                else        ((u16*)Cv)[idx] = f2bits(v);
            }
        }
    }
}

// ---------- MFMA flash attention: one block per (b,p,h), wave = 64 query rows ----------
__global__ __launch_bounds__(256)
void attn_mfma(const u16* __restrict__ qkv, u16* __restrict__ out)
{
    __shared__ u16 Kt[64*72];
    __shared__ u16 Vt[64*72];
    __shared__ u16 Pw[4][64*72];
    const int tid = threadIdx.x;
    const int wave = tid >> 6, lane = tid & 63;
    const int lr = lane & 15, quad = lane >> 4;
    const int bp = blockIdx.x >> 3, h = blockIdx.x & 7;
    const u16* base = qkv + (size_t)bp * NN * (3*DIM);
    const int qo = h*DHEAD, ko = DIM + h*DHEAD, vo = 2*DIM + h*DHEAD;
    const int m0 = wave * 64;

    bf16x8 qf[4][2];
#pragma unroll
    for (int i = 0; i < 4; ++i)
#pragma unroll
        for (int kb = 0; kb < 2; ++kb)
            qf[i][kb] = *(const bf16x8*)(base + (size_t)(m0 + i*16 + lr)*(3*DIM)
                                         + qo + kb*32 + quad*8);

    f32x4 o[4][4] = {};
    float mrow[4][4], lrow[4][4];
#pragma unroll
    for (int i = 0; i < 4; ++i)
#pragma unroll
        for (int r = 0; r < 4; ++r) { mrow[i][r] = -1e30f; lrow[i][r] = 0.f; }

    const int sr = tid >> 3, sc = tid & 7;

    for (int t = 0; t < 4; ++t) {
        __syncthreads();
#pragma unroll
        for (int half = 0; half < 2; ++half) {
            const int key = half*32 + sr;
            const u16* krow = base + (size_t)(t*64 + key)*(3*DIM);
            uint4 kv = *(const uint4*)(krow + ko + sc*8);
            *(uint4*)(Kt + key*72 + sc*8) = kv;
            uint4 vv = *(const uint4*)(krow + vo + sc*8);
            const int d0 = sc*8;
            Vt[(d0+0)*72 + key] = (u16)(vv.x & 0xffffu);
            Vt[(d0+1)*72 + key] = (u16)(vv.x >> 16);
            Vt[(d0+2)*72 + key] = (u16)(vv.y & 0xffffu);
            Vt[(d0+3)*72 + key] = (u16)(vv.y >> 16);
            Vt[(d0+4)*72 + key] = (u16)(vv.z & 0xffffu);
            Vt[(d0+5)*72 + key] = (u16)(vv.z >> 16);
            Vt[(d0+6)*72 + key] = (u16)(vv.w & 0xffffu);
            Vt[(d0+7)*72 + key] = (u16)(vv.w >> 16);
        }
        __syncthreads();

        f32x4 s[4][4] = {};
        bf16x8 kf[4][2];
#pragma unroll
        for (int j = 0; j < 4; ++j)
#pragma unroll
            for (int kb = 0; kb < 2; ++kb)
                kf[j][kb] = *(const bf16x8*)(Kt + (j*16 + lr)*72 + kb*32 + quad*8);
#pragma unroll
        for (int i = 0; i < 4; ++i)
#pragma unroll
            for (int j = 0; j < 4; ++j)
#pragma unroll
                for (int kb = 0; kb < 2; ++kb)
                    s[i][j] = __builtin_amdgcn_mfma_f32_16x16x32_bf16(
                        qf[i][kb], kf[j][kb], s[i][j], 0, 0, 0);

        float alpha[4][4];
#pragma unroll
        for (int i = 0; i < 4; ++i)
#pragma unroll
            for (int r = 0; r < 4; ++r) {
#pragma unroll
                for (int j = 0; j < 4; ++j) s[i][j][r] *= 0.125f;
                float mt = fmaxf(fmaxf(s[i][0][r], s[i][1][r]),
                                 fmaxf(s[i][2][r], s[i][3][r]));
#pragma unroll
                for (int off = 1; off <= 8; off <<= 1) mt = fmaxf(mt, __shfl_xor(mt, off));
                const float mn = fmaxf(mrow[i][r], mt);
                alpha[i][r] = __expf(mrow[i][r] - mn);
                mrow[i][r] = mn;
                float ssum = 0.f;
#pragma unroll
                for (int j = 0; j < 4; ++j) {
                    const float p = __expf(s[i][j][r] - mn);
                    s[i][j][r] = p; ssum += p;
                }
#pragma unroll
                for (int off = 1; off <= 8; off <<= 1) ssum += __shfl_xor(ssum, off);
                lrow[i][r] = lrow[i][r]*alpha[i][r] + ssum;
            }

#pragma unroll
        for (int i = 0; i < 4; ++i)
#pragma unroll
            for (int j = 0; j < 4; ++j)
#pragma unroll
                for (int r = 0; r < 4; ++r)
                    Pw[wave][(i*16 + quad*4 + r)*72 + j*16 + lr] = f2bits(s[i][j][r]);
        __syncthreads();

#pragma unroll
        for (int i = 0; i < 4; ++i)
#pragma unroll
            for (int jd = 0; jd < 4; ++jd)
#pragma unroll
                for (int r = 0; r < 4; ++r)
                    o[i][jd][r] *= alpha[i][r];

        bf16x8 af[4][2], bv[4][2];
#pragma unroll
        for (int i = 0; i < 4; ++i)
#pragma unroll
            for (int kb = 0; kb < 2; ++kb)
                af[i][kb] = *(const bf16x8*)(Pw[wave] + (i*16 + lr)*72 + kb*32 + quad*8);
#pragma unroll
        for (int jd = 0; jd < 4; ++jd)
#pragma unroll
            for (int kb = 0; kb < 2; ++kb)
                bv[jd][kb] = *(const bf16x8*)(Vt + (jd*16 + lr)*72 + kb*32 + quad*8);
#pragma unroll
        for (int i = 0; i < 4; ++i)
#pragma unroll
            for (int jd = 0; jd < 4; ++jd)
#pragma unroll
                for (int kb = 0; kb < 2; ++kb)
                    o[i][jd] = __builtin_amdgcn_mfma_f32_16x16x32_bf16(
                        af[i][kb], bv[jd][kb], o[i][jd], 0, 0, 0);
    }

#pragma unroll
    for (int i = 0; i < 4; ++i)
#pragma unroll
        for (int r = 0; r < 4; ++r) {
            const float inv = 1.0f / lrow[i][r];
            const size_t rowg = (size_t)bp*NN + m0 + i*16 + quad*4 + r;
#pragma unroll
            for (int jd = 0; jd < 4; ++jd)
                out[rowg*DIM + h*DHEAD + jd*16 + lr] = f2bits(o[i][jd][r] * inv);
        }
}

// ---------- LayerNorm over DIM=512, fp32 in, bf16 out; one wave per row; float4 ----------
__global__ __launch_bounds__(256)
void ln_kernel(const float* __restrict__ x, const float* __restrict__ g,
               const float* __restrict__ b, u16* __restrict__ y, int rows)
{
    const int wave = threadIdx.x >> 6, lane = threadIdx.x & 63;
    const int row = blockIdx.x * 4 + wave;
    if (row >= rows) return;
    const float4* xr = (const float4*)(x + (size_t)row * DIM);
    float4 v0 = xr[lane], v1 = xr[lane + 64];
    float s  = v0.x+v0.y+v0.z+v0.w + v1.x+v1.y+v1.z+v1.w;
    float s2 = v0.x*v0.x+v0.y*v0.y+v0.z*v0.z+v0.w*v0.w
             + v1.x*v1.x+v1.y*v1.y+v1.z*v1.z+v1.w*v1.w;
#pragma unroll
    for (int off = 32; off; off >>= 1) { s += __shfl_xor(s, off); s2 += __shfl_xor(s2, off); }
    const float mean = s * (1.f/512.f);
    const float var  = s2 * (1.f/512.f) - mean*mean;
    const float rstd = rsqrtf(var + 1e-5f);
    const float4* gp = (const float4*)g; const float4* bp = (const float4*)b;
    float4 g0 = gp[lane], g1 = gp[lane+64], b0 = bp[lane], b1 = bp[lane+64];
    ushort4 o0, o1;
    o0.x = f2bits((v0.x-mean)*rstd*g0.x + b0.x);
    o0.y = f2bits((v0.y-mean)*rstd*g0.y + b0.y);
    o0.z = f2bits((v0.z-mean)*rstd*g0.z + b0.z);
    o0.w = f2bits((v0.w-mean)*rstd*g0.w + b0.w);
    o1.x = f2bits((v1.x-mean)*rstd*g1.x + b1.x);
    o1.y = f2bits((v1.y-mean)*rstd*g1.y + b1.y);
    o1.z = f2bits((v1.z-mean)*rstd*g1.z + b1.z);
    o1.w = f2bits((v1.w-mean)*rstd*g1.w + b1.w);
    ushort4* yr = (ushort4*)(y + (size_t)row * DIM);
    yr[lane] = o0; yr[lane+64] = o1;
}

// ---------- fused BiAttn LN + mean over P: block=(b,n), wave p=0..3 ----------
__global__ __launch_bounds__(256)
void lnmean_kernel(const float* __restrict__ x, const float* __restrict__ g,
                   const float* __restrict__ b, u16* __restrict__ y,
                   u16* __restrict__ G)
{
    __shared__ float T[4][512];
    const int wave = threadIdx.x >> 6, lane = threadIdx.x & 63;
    const int bb = blockIdx.x >> 8, n = blockIdx.x & 255;
    const int row = (bb*PP + wave)*NN + n;
    const float4* xr = (const float4*)(x + (size_t)row * DIM);
    float4 v0 = xr[lane], v1 = xr[lane + 64];
    float s  = v0.x+v0.y+v0.z+v0.w + v1.x+v1.y+v1.z+v1.w;
    float s2 = v0.x*v0.x+v0.y*v0.y+v0.z*v0.z+v0.w*v0.w
             + v1.x*v1.x+v1.y*v1.y+v1.z*v1.z+v1.w*v1.w;
#pragma unroll
    for (int off = 32; off; off >>= 1) { s += __shfl_xor(s, off); s2 += __shfl_xor(s2, off); }
    const float mean = s * (1.f/512.f);
    const float var  = s2 * (1.f/512.f) - mean*mean;
    const float rstd = rsqrtf(var + 1e-5f);
    const float4* gp = (const float4*)g; const float4* bp = (const float4*)b;
    float4 g0 = gp[lane], g1 = gp[lane+64], b0 = bp[lane], b1 = bp[lane+64];
    float4 y0, y1;
    y0.x = (v0.x-mean)*rstd*g0.x + b0.x;
    y0.y = (v0.y-mean)*rstd*g0.y + b0.y;
    y0.z = (v0.z-mean)*rstd*g0.z + b0.z;
    y0.w = (v0.w-mean)*rstd*g0.w + b0.w;
    y1.x = (v1.x-mean)*rstd*g1.x + b1.x;
    y1.y = (v1.y-mean)*rstd*g1.y + b1.y;
    y1.z = (v1.z-mean)*rstd*g1.z + b1.z;
    y1.w = (v1.w-mean)*rstd*g1.w + b1.w;
    ushort4 o0, o1;
    o0.x = f2bits(y0.x); o0.y = f2bits(y0.y); o0.z = f2bits(y0.z); o0.w = f2bits(y0.w);
    o1.x = f2bits(y1.x); o1.y = f2bits(y1.y); o1.z = f2bits(y1.z); o1.w = f2bits(y1.w);
    ushort4* yr = (ushort4*)(y + (size_t)row * DIM);
    yr[lane] = o0; yr[lane+64] = o1;
    *(float4*)&T[wave][lane*4]       = y0;
    *(float4*)&T[wave][256 + lane*4] = y1;
    __syncthreads();
    const int d0 = threadIdx.x;   // 0..255, handles d0 and d0+256
    const float m0 = (T[0][d0]     + T[1][d0]     + T[2][d0]     + T[3][d0])     * 0.25f;
    const float m1 = (T[0][d0+256] + T[1][d0+256] + T[2][d0+256] + T[3][d0+256]) * 0.25f;
    u16* gr = G + ((size_t)bb*NN + n)*DIM;
    gr[d0]       = f2bits(m0);
    gr[d0 + 256] = f2bits(m1);
}

// ---------- fused s_attn + fuse: wave per row; s in-register, then update ----------
__global__ __launch_bounds__(256)
void fuse2_kernel(const float4* __restrict__ xb, const float4* __restrict__ m1,
                  const u16* __restrict__ ca, const u16* __restrict__ xl,
                  const u16* __restrict__ xg, const float* __restrict__ wsv,
                  const float* __restrict__ bs, float4* __restrict__ xa)
{
    const int wave = threadIdx.x >> 6, lane = threadIdx.x & 63;
    const int row = blockIdx.x * 4 + wave;
    const int b = row >> 10, n = row & 255;
    const u16* xlr = xl + (size_t)row * RED;
    const u16* xgr = xg + ((size_t)b*NN + n) * RED;
    float s = bits2f(xlr[lane])    * wsv[lane]
            + bits2f(xlr[lane+64]) * wsv[lane+64]
            + bits2f(xgr[lane])    * wsv[RED+lane]
            + bits2f(xgr[lane+64]) * wsv[RED+64+lane];
#pragma unroll
    for (int off = 32; off; off >>= 1) s += __shfl_xor(s, off);
    s = 1.f / (1.f + __expf(-(s + bs[0])));
    const u16* car = ca + ((((size_t)b << 8) + n)*DIM);
#pragma unroll
    for (int t = 0; t < 2; ++t) {
        const int dg = lane + t*64;
        const size_t idx = (size_t)row*128 + dg;
        ushort4 cu = *(const ushort4*)(car + dg*4);
        float4 xv = xb[idx], mv = m1[idx], o;
        o.x = xv.x + mv.x * bits2f(cu.x) * s;
        o.y = xv.y + mv.y * bits2f(cu.y) * s;
        o.z = xv.z + mv.z * bits2f(cu.z) * s;
        o.w = xv.w + mv.w * bits2f(cu.w) * s;
        xa[idx] = o;
    }
}

// ---------- host launch ----------
extern "C" void kernel_launch(void* const* d_in, const int* in_sizes, int n_in,
                              void* d_out, int out_size, void* d_ws, size_t ws_size,
                              hipStream_t stream)
{
    const float* x_in  = (const float*)d_in[0];
    const float* ln1_g = (const float*)d_in[1];
    const float* ln1_b = (const float*)d_in[2];
    const float* w_qkv = (const float*)d_in[3];
    const float* w_o   = (const float*)d_in[4];
    const float* b_o   = (const float*)d_in[5];
    const float* ln2_g = (const float*)d_in[6];
    const float* ln2_b = (const float*)d_in[7];
    const float* w1    = (const float*)d_in[8];
    const float* b1    = (const float*)d_in[9];
    const float* w2    = (const float*)d_in[10];
    const float* b2    = (const float*)d_in[11];
    const float* bn_g  = (const float*)d_in[12];
    const float* bn_b  = (const float*)d_in[13];
    const float* wg    = (const float*)d_in[14];
    const float* bg    = (const float*)d_in[15];
    const float* wl    = (const float*)d_in[16];
    const float* bl    = (const float*)d_in[17];
    const float* wc    = (const float*)d_in[18];
    const float* bc    = (const float*)d_in[19];
    const float* wsw   = (const float*)d_in[20];
    const float* bsb   = (const float*)d_in[21];

    char* ws = (char*)d_ws;
    auto alloc = [&](size_t bytes) {
        char* p = ws;
        ws += (bytes + 255) & ~(size_t)255;
        return p;
    };
    float* XA = (float*)alloc(XELEMS * 4);
    float* XB = (float*)alloc(XELEMS * 4);
    float* M1 = (float*)alloc(XELEMS * 4);
    u16*   L  = (u16*)  alloc(XELEMS * 2);
    u16*   Q  = (u16*)  alloc((size_t)ROWS * 3*DIM * 2);
    u16*   H  = (u16*)  alloc((size_t)ROWS * MLPD * 2);
    u16*   G  = (u16*)  alloc((size_t)BB*NN*DIM * 2);
    u16*   G2 = (u16*)  alloc((size_t)BB*NN*RED * 2);
    u16*   XL = (u16*)  alloc((size_t)ROWS*RED * 2);
    u16*   CA = (u16*)  alloc((size_t)BB*NN*DIM * 2);
    // all-layer transposed bf16 weights
    u16* WTqkv = (u16*)alloc((size_t)DEPTH*DIM*3*DIM * 2);
    u16* WTo   = (u16*)alloc((size_t)DEPTH*DIM*DIM * 2);
    u16* WT1   = (u16*)alloc((size_t)DEPTH*DIM*MLPD * 2);
    u16* WT2   = (u16*)alloc((size_t)DEPTH*MLPD*DIM * 2);
    u16* WTl   = (u16*)alloc((size_t)DEPTH*DIM*RED * 2);
    u16* WTg   = (u16*)alloc((size_t)DEPTH*DIM*RED * 2);
    u16* WTc   = (u16*)alloc((size_t)DEPTH*RED*DIM * 2);

    // ---- all weight transposes upfront, batched over depth ----
    wtrans_all<<<dim3(48,16,DEPTH), 256, 0, stream>>>(w_qkv, WTqkv, DIM, 3*DIM);
    wtrans_all<<<dim3(16,16,DEPTH), 256, 0, stream>>>(w_o,   WTo,   DIM, DIM);
    wtrans_all<<<dim3(64,16,DEPTH), 256, 0, stream>>>(w1,    WT1,   DIM, MLPD);
    wtrans_all<<<dim3(16,64,DEPTH), 256, 0, stream>>>(w2,    WT2,   MLPD, DIM);
    wtrans_all<<<dim3(4,16,DEPTH),  256, 0, stream>>>(wl,    WTl,   DIM, RED);
    wtrans_all<<<dim3(4,16,DEPTH),  256, 0, stream>>>(wg,    WTg,   DIM, RED);
    wtrans_all<<<dim3(16,4,DEPTH),  256, 0, stream>>>(wc,    WTc,   RED, DIM);

    for (int l = 0; l < DEPTH; ++l) {
        const float* Xres = l ? (const float*)XA : x_in;   // layer-0 reads input directly
        // ---- attention block ----
        ln_kernel<<<ROWS/4, 256, 0, stream>>>(Xres, ln1_g + l*DIM, ln1_b + l*DIM, L, ROWS);
        gemm_db<64,128,64,2,2><<<dim3(128,12), 256, 0, stream>>>(
            L, WTqkv + (size_t)l*DIM*3*DIM, nullptr, nullptr, Q, ROWS, 3*DIM, DIM, 0, 0);
        attn_mfma<<<BB*PP*HEADS, 256, 0, stream>>>(Q, L);
        gemm_db<64,128,64,2,2><<<dim3(128,4), 256, 0, stream>>>(
            L, WTo + (size_t)l*DIM*DIM, b_o + l*DIM, Xres, XB, ROWS, DIM, DIM, 0, 1);

        // ---- MLP ----
        ln_kernel<<<ROWS/4, 256, 0, stream>>>(XB, ln2_g + l*DIM, ln2_b + l*DIM, Q, ROWS);
        gemm_db<64,64,64,2,2><<<dim3(128,32), 256, 0, stream>>>(
            Q, WT1 + (size_t)l*DIM*MLPD, b1 + l*MLPD, nullptr, H, ROWS, MLPD, DIM, 1, 0);
        gemm_db<64,128,64,2,2><<<dim3(128,4), 256, 0, stream>>>(
            H, WT2 + (size_t)l*MLPD*DIM, b2 + l*DIM, nullptr, M1, ROWS, DIM, MLPD, 0, 1);

        // ---- BiAttn ----
        lnmean_kernel<<<BB*NN, 256, 0, stream>>>(M1, bn_g + l*DIM, bn_b + l*DIM, L, G);
        gemm_db<64,64,64,2,2><<<dim3(32,2), 256, 0, stream>>>(
            G, WTg + (size_t)l*DIM*RED, bg + l*RED, nullptr, G2, BB*NN, RED, DIM, 1, 0);
        gemm_db<64,64,64,2,2><<<dim3(128,2), 256, 0, stream>>>(
            L, WTl + (size_t)l*DIM*RED, bl + l*RED, nullptr, XL, ROWS, RED, DIM, 1, 0);
        gemm_db<64,64,64,2,2><<<dim3(32,8), 256, 0, stream>>>(
            G2, WTc + (size_t)l*RED*DIM, bc + l*DIM, nullptr, CA, BB*NN, DIM, RED, 2, 0);
        // fused s_attn + gating + residual; last layer writes d_out directly
        fuse2_kernel<<<ROWS/4, 256, 0, stream>>>((const float4*)XB, (const float4*)M1,
                                                 CA, XL, G2, wsw + (size_t)l*2*RED, bsb + l,
                                                 (l == DEPTH-1) ? (float4*)d_out
                                                                : (float4*)XA);
    }
}

// Round 8
// 912.181 us; speedup vs baseline: 1.4149x; 1.0366x over previous
//
#include <hip/hip_runtime.h>
#include <hip/hip_bf16.h>
#include <math.h>

typedef __hip_bfloat16 bf16;
typedef unsigned short u16;
typedef __bf16 bf16x8 __attribute__((ext_vector_type(8)));
typedef float f32x4 __attribute__((ext_vector_type(4)));

// ---------- helpers ----------
__device__ __forceinline__ float b2f(bf16 v) { return __bfloat162float(v); }
__device__ __forceinline__ bf16 f2b(float v) { return __float2bfloat16(v); }
__device__ __forceinline__ float bits2f(unsigned int u) {
    union { unsigned int i; float f; } w; w.i = u << 16; return w.f;
}
__device__ __forceinline__ u16 f2bits(float v) {
    union { bf16 h; u16 u; } w; w.h = __float2bfloat16(v); return w.u;
}
__device__ __forceinline__ void async16(void* lds, const void* g) {
    __builtin_amdgcn_global_load_lds(
        (const __attribute__((address_space(1))) unsigned int*)g,
        (__attribute__((address_space(3))) unsigned int*)lds, 16, 0, 0);
}

#define DEPTH 4
#define HEADS 8
#define DHEAD 64
#define DIM 512
#define MLPD 2048
#define RED 128
#define BB 8
#define PP 4
#define NN 256
#define ROWS (BB*PP*NN)          // 8192 tokens
#define XELEMS ((size_t)ROWS*DIM) // 4194304

// ---------- batched weight transpose+cast: W fp32 [D][K][N] -> WT bf16 [D][N][K] ----------
__global__ __launch_bounds__(256)
void wtrans_all(const float* __restrict__ W, u16* __restrict__ WT, int K, int N)
{
    __shared__ float T[32][33];
    const int l = blockIdx.z;
    W  += (size_t)l * K * N;
    WT += (size_t)l * N * K;
    const int tx = threadIdx.x & 31, ty = threadIdx.x >> 5; // ty 0..7
    const int n0 = blockIdx.x * 32, k0 = blockIdx.y * 32;
#pragma unroll
    for (int r = 0; r < 4; ++r)
        T[ty + r*8][tx] = W[(size_t)(k0 + ty + r*8) * N + n0 + tx];
    __syncthreads();
#pragma unroll
    for (int r = 0; r < 4; ++r)
        WT[(size_t)(n0 + ty + r*8) * K + k0 + tx] = f2bits(T[tx][ty + r*8]);
}

// ---------- double-buffered MFMA GEMM (2-phase): C = act(A @ WT^T + bias) [+res]
template<int BM, int BN, int BK, int WROWS, int WCOLS>
__global__ __launch_bounds__(256)
void gemm_db(const u16* __restrict__ A, const u16* __restrict__ WT,
             const float* __restrict__ bias, const float* __restrict__ res,
             void* __restrict__ Cv, int M, int N, int K, int act, int outf32)
{
    constexpr int KG  = BK/8;        // 16B k-groups per row
    constexpr int RPC = 512/BK;      // rows per 1KB staging chunk
    constexpr int NCA = BM*BK/512;   // A chunks
    constexpr int NCB = BN*BK/512;   // B chunks
    constexpr int CPT = (NCA+NCB)/4; // chunks per wave
    constexpr int WM = BM/WROWS, WN = BN/WCOLS;
    constexpr int AM = WM/16, AN = WN/16, KB = BK/32;

    __shared__ u16 As[2][BM*BK];
    __shared__ u16 Bs[2][BN*BK];
    const int tid = threadIdx.x, wave = tid >> 6, lane = tid & 63;
    const int bm = blockIdx.x * BM;
    const int bn = blockIdx.y * BN;
    const int wm = (wave / WCOLS) * WM, wn = (wave % WCOLS) * WN;
    const int lr = lane & 15, quad = lane >> 4;

    const int rowc = lane / KG;
    const int kgs  = ((lane & (KG-1)) ^ (KG == 4 ? ((rowc >> 1) & 3) : (rowc & 7))) * 8;

    auto stage = [&](int buf, int k0) {
#pragma unroll
        for (int t = 0; t < CPT; ++t) {
            const int c = wave*CPT + t;
            if (c < NCA)
                async16(&As[buf][c*512], A  + (size_t)(bm + c*RPC + rowc) * K + k0 + kgs);
            else
                async16(&Bs[buf][(c-NCA)*512], WT + (size_t)(bn + (c-NCA)*RPC + rowc) * K + k0 + kgs);
        }
    };

    f32x4 acc[AM][AN] = {};

    stage(0, 0);
    __syncthreads();

    const int NK = K / BK;
    for (int ki = 0; ki < NK; ++ki) {
        const int cur = ki & 1;
        if (ki + 1 < NK) stage(cur ^ 1, (ki + 1) * BK);

        bf16x8 af[AM][KB], bv[AN][KB];
#pragma unroll
        for (int i = 0; i < AM; ++i) {
            const int rA = wm + i*16 + lr;
            const int sw = (KG == 4 ? (((rA & 15) >> 1) & 3) : (rA & 7));
#pragma unroll
            for (int kb = 0; kb < KB; ++kb)
                af[i][kb] = *(const bf16x8*)(As[cur] + rA*BK + (((kb*4 + quad) ^ sw) * 8));
        }
#pragma unroll
        for (int j = 0; j < AN; ++j) {
            const int rB = wn + j*16 + lr;
            const int sw = (KG == 4 ? (((rB & 15) >> 1) & 3) : (rB & 7));
#pragma unroll
            for (int kb = 0; kb < KB; ++kb)
                bv[j][kb] = *(const bf16x8*)(Bs[cur] + rB*BK + (((kb*4 + quad) ^ sw) * 8));
        }
#pragma unroll
        for (int i = 0; i < AM; ++i)
#pragma unroll
            for (int j = 0; j < AN; ++j)
#pragma unroll
                for (int kb = 0; kb < KB; ++kb)
                    acc[i][j] = __builtin_amdgcn_mfma_f32_16x16x32_bf16(
                        af[i][kb], bv[j][kb], acc[i][j], 0, 0, 0);
        __syncthreads();
    }

#pragma unroll
    for (int i = 0; i < AM; ++i) {
        const int rowb = bm + wm + i*16 + quad*4;
#pragma unroll
        for (int j = 0; j < AN; ++j) {
            const int col = bn + wn + j*16 + lr;
            const float bvs = bias ? bias[col] : 0.f;
#pragma unroll
            for (int r = 0; r < 4; ++r) {
                float v = acc[i][j][r] + bvs;
                if (act == 1) v = 0.5f * v * (1.0f + erff(v * 0.70710678118f));
                else if (act == 2) v = 1.0f / (1.0f + __expf(-v));
                const size_t idx = (size_t)(rowb + r) * N + col;
                if (res) v += res[idx];
                if (outf32) ((float*)Cv)[idx] = v;
                else        ((u16*)Cv)[idx] = f2bits(v);
            }
        }
    }
}

// ---------- MFMA flash attention, split-Q: one block per (b,p,h,qhalf) ----------
// Grid 512 -> 2 blocks/CU co-resident (independent barrier domains): one block's
// K/V staging overlaps the other's MFMA. 4 waves x 32 q-rows each; LDS 36 KB.
__global__ __launch_bounds__(256)
void attn_mfma(const u16* __restrict__ qkv, u16* __restrict__ out)
{
    __shared__ u16 Kt[64*72];
    __shared__ u16 Vt[64*72];
    __shared__ u16 Pw[4][32*72];
    const int tid = threadIdx.x;
    const int wave = tid >> 6, lane = tid & 63;
    const int lr = lane & 15, quad = lane >> 4;
    const int bp = blockIdx.x >> 4;          // (b,p)
    const int h  = (blockIdx.x >> 1) & 7;    // head
    const int qh = blockIdx.x & 1;           // query half
    const u16* base = qkv + (size_t)bp * NN * (3*DIM);
    const int qo = h*DHEAD, ko = DIM + h*DHEAD, vo = 2*DIM + h*DHEAD;
    const int m0 = qh*128 + wave*32;

    bf16x8 qf[2][2];
#pragma unroll
    for (int i = 0; i < 2; ++i)
#pragma unroll
        for (int kb = 0; kb < 2; ++kb)
            qf[i][kb] = *(const bf16x8*)(base + (size_t)(m0 + i*16 + lr)*(3*DIM)
                                         + qo + kb*32 + quad*8);

    f32x4 o[2][4] = {};
    float mrow[2][4], lrow[2][4];
#pragma unroll
    for (int i = 0; i < 2; ++i)
#pragma unroll
        for (int r = 0; r < 4; ++r) { mrow[i][r] = -1e30f; lrow[i][r] = 0.f; }

    const int sr = tid >> 3, sc = tid & 7;

    for (int t = 0; t < 4; ++t) {
        __syncthreads();
#pragma unroll
        for (int half = 0; half < 2; ++half) {
            const int key = half*32 + sr;
            const u16* krow = base + (size_t)(t*64 + key)*(3*DIM);
            uint4 kv = *(const uint4*)(krow + ko + sc*8);
            *(uint4*)(Kt + key*72 + sc*8) = kv;
            uint4 vv = *(const uint4*)(krow + vo + sc*8);
            const int d0 = sc*8;
            Vt[(d0+0)*72 + key] = (u16)(vv.x & 0xffffu);
            Vt[(d0+1)*72 + key] = (u16)(vv.x >> 16);
            Vt[(d0+2)*72 + key] = (u16)(vv.y & 0xffffu);
            Vt[(d0+3)*72 + key] = (u16)(vv.y >> 16);
            Vt[(d0+4)*72 + key] = (u16)(vv.z & 0xffffu);
            Vt[(d0+5)*72 + key] = (u16)(vv.z >> 16);
            Vt[(d0+6)*72 + key] = (u16)(vv.w & 0xffffu);
            Vt[(d0+7)*72 + key] = (u16)(vv.w >> 16);
        }
        __syncthreads();

        f32x4 s[2][4] = {};
        bf16x8 kf[4][2];
#pragma unroll
        for (int j = 0; j < 4; ++j)
#pragma unroll
            for (int kb = 0; kb < 2; ++kb)
                kf[j][kb] = *(const bf16x8*)(Kt + (j*16 + lr)*72 + kb*32 + quad*8);
#pragma unroll
        for (int i = 0; i < 2; ++i)
#pragma unroll
            for (int j = 0; j < 4; ++j)
#pragma unroll
                for (int kb = 0; kb < 2; ++kb)
                    s[i][j] = __builtin_amdgcn_mfma_f32_16x16x32_bf16(
                        qf[i][kb], kf[j][kb], s[i][j], 0, 0, 0);

        float alpha[2][4];
#pragma unroll
        for (int i = 0; i < 2; ++i)
#pragma unroll
            for (int r = 0; r < 4; ++r) {
#pragma unroll
                for (int j = 0; j < 4; ++j) s[i][j][r] *= 0.125f;
                float mt = fmaxf(fmaxf(s[i][0][r], s[i][1][r]),
                                 fmaxf(s[i][2][r], s[i][3][r]));
#pragma unroll
                for (int off = 1; off <= 8; off <<= 1) mt = fmaxf(mt, __shfl_xor(mt, off));
                const float mn = fmaxf(mrow[i][r], mt);
                alpha[i][r] = __expf(mrow[i][r] - mn);
                mrow[i][r] = mn;
                float ssum = 0.f;
#pragma unroll
                for (int j = 0; j < 4; ++j) {
                    const float p = __expf(s[i][j][r] - mn);
                    s[i][j][r] = p; ssum += p;
                }
#pragma unroll
                for (int off = 1; off <= 8; off <<= 1) ssum += __shfl_xor(ssum, off);
                lrow[i][r] = lrow[i][r]*alpha[i][r] + ssum;
            }

#pragma unroll
        for (int i = 0; i < 2; ++i)
#pragma unroll
            for (int j = 0; j < 4; ++j)
#pragma unroll
                for (int r = 0; r < 4; ++r)
                    Pw[wave][(i*16 + quad*4 + r)*72 + j*16 + lr] = f2bits(s[i][j][r]);
        __syncthreads();

#pragma unroll
        for (int i = 0; i < 2; ++i)
#pragma unroll
            for (int jd = 0; jd < 4; ++jd)
#pragma unroll
                for (int r = 0; r < 4; ++r)
                    o[i][jd][r] *= alpha[i][r];

        bf16x8 af[2][2], bv[4][2];
#pragma unroll
        for (int i = 0; i < 2; ++i)
#pragma unroll
            for (int kb = 0; kb < 2; ++kb)
                af[i][kb] = *(const bf16x8*)(Pw[wave] + (i*16 + lr)*72 + kb*32 + quad*8);
#pragma unroll
        for (int jd = 0; jd < 4; ++jd)
#pragma unroll
            for (int kb = 0; kb < 2; ++kb)
                bv[jd][kb] = *(const bf16x8*)(Vt + (jd*16 + lr)*72 + kb*32 + quad*8);
#pragma unroll
        for (int i = 0; i < 2; ++i)
#pragma unroll
            for (int jd = 0; jd < 4; ++jd)
#pragma unroll
                for (int kb = 0; kb < 2; ++kb)
                    o[i][jd] = __builtin_amdgcn_mfma_f32_16x16x32_bf16(
                        af[i][kb], bv[jd][kb], o[i][jd], 0, 0, 0);
    }

#pragma unroll
    for (int i = 0; i < 2; ++i)
#pragma unroll
        for (int r = 0; r < 4; ++r) {
            const float inv = 1.0f / lrow[i][r];
            const size_t rowg = (size_t)bp*NN + m0 + i*16 + quad*4 + r;
#pragma unroll
            for (int jd = 0; jd < 4; ++jd)
                out[rowg*DIM + h*DHEAD + jd*16 + lr] = f2bits(o[i][jd][r] * inv);
        }
}

// ---------- LayerNorm over DIM=512, fp32 in, bf16 out; one wave per row; float4 ----------
__global__ __launch_bounds__(256)
void ln_kernel(const float* __restrict__ x, const float* __restrict__ g,
               const float* __restrict__ b, u16* __restrict__ y, int rows)
{
    const int wave = threadIdx.x >> 6, lane = threadIdx.x & 63;
    const int row = blockIdx.x * 4 + wave;
    if (row >= rows) return;
    const float4* xr = (const float4*)(x + (size_t)row * DIM);
    float4 v0 = xr[lane], v1 = xr[lane + 64];
    float s  = v0.x+v0.y+v0.z+v0.w + v1.x+v1.y+v1.z+v1.w;
    float s2 = v0.x*v0.x+v0.y*v0.y+v0.z*v0.z+v0.w*v0.w
             + v1.x*v1.x+v1.y*v1.y+v1.z*v1.z+v1.w*v1.w;
#pragma unroll
    for (int off = 32; off; off >>= 1) { s += __shfl_xor(s, off); s2 += __shfl_xor(s2, off); }
    const float mean = s * (1.f/512.f);
    const float var  = s2 * (1.f/512.f) - mean*mean;
    const float rstd = rsqrtf(var + 1e-5f);
    const float4* gp = (const float4*)g; const float4* bp = (const float4*)b;
    float4 g0 = gp[lane], g1 = gp[lane+64], b0 = bp[lane], b1 = bp[lane+64];
    ushort4 o0, o1;
    o0.x = f2bits((v0.x-mean)*rstd*g0.x + b0.x);
    o0.y = f2bits((v0.y-mean)*rstd*g0.y + b0.y);
    o0.z = f2bits((v0.z-mean)*rstd*g0.z + b0.z);
    o0.w = f2bits((v0.w-mean)*rstd*g0.w + b0.w);
    o1.x = f2bits((v1.x-mean)*rstd*g1.x + b1.x);
    o1.y = f2bits((v1.y-mean)*rstd*g1.y + b1.y);
    o1.z = f2bits((v1.z-mean)*rstd*g1.z + b1.z);
    o1.w = f2bits((v1.w-mean)*rstd*g1.w + b1.w);
    ushort4* yr = (ushort4*)(y + (size_t)row * DIM);
    yr[lane] = o0; yr[lane+64] = o1;
}

// ---------- fused BiAttn LN + mean over P: block=(b,n), wave p=0..3 ----------
__global__ __launch_bounds__(256)
void lnmean_kernel(const float* __restrict__ x, const float* __restrict__ g,
                   const float* __restrict__ b, u16* __restrict__ y,
                   u16* __restrict__ G)
{
    __shared__ float T[4][512];
    const int wave = threadIdx.x >> 6, lane = threadIdx.x & 63;
    const int bb = blockIdx.x >> 8, n = blockIdx.x & 255;
    const int row = (bb*PP + wave)*NN + n;
    const float4* xr = (const float4*)(x + (size_t)row * DIM);
    float4 v0 = xr[lane], v1 = xr[lane + 64];
    float s  = v0.x+v0.y+v0.z+v0.w + v1.x+v1.y+v1.z+v1.w;
    float s2 = v0.x*v0.x+v0.y*v0.y+v0.z*v0.z+v0.w*v0.w
             + v1.x*v1.x+v1.y*v1.y+v1.z*v1.z+v1.w*v1.w;
#pragma unroll
    for (int off = 32; off; off >>= 1) { s += __shfl_xor(s, off); s2 += __shfl_xor(s2, off); }
    const float mean = s * (1.f/512.f);
    const float var  = s2 * (1.f/512.f) - mean*mean;
    const float rstd = rsqrtf(var + 1e-5f);
    const float4* gp = (const float4*)g; const float4* bp = (const float4*)b;
    float4 g0 = gp[lane], g1 = gp[lane+64], b0 = bp[lane], b1 = bp[lane+64];
    float4 y0, y1;
    y0.x = (v0.x-mean)*rstd*g0.x + b0.x;
    y0.y = (v0.y-mean)*rstd*g0.y + b0.y;
    y0.z = (v0.z-mean)*rstd*g0.z + b0.z;
    y0.w = (v0.w-mean)*rstd*g0.w + b0.w;
    y1.x = (v1.x-mean)*rstd*g1.x + b1.x;
    y1.y = (v1.y-mean)*rstd*g1.y + b1.y;
    y1.z = (v1.z-mean)*rstd*g1.z + b1.z;
    y1.w = (v1.w-mean)*rstd*g1.w + b1.w;
    ushort4 o0, o1;
    o0.x = f2bits(y0.x); o0.y = f2bits(y0.y); o0.z = f2bits(y0.z); o0.w = f2bits(y0.w);
    o1.x = f2bits(y1.x); o1.y = f2bits(y1.y); o1.z = f2bits(y1.z); o1.w = f2bits(y1.w);
    ushort4* yr = (ushort4*)(y + (size_t)row * DIM);
    yr[lane] = o0; yr[lane+64] = o1;
    *(float4*)&T[wave][lane*4]       = y0;
    *(float4*)&T[wave][256 + lane*4] = y1;
    __syncthreads();
    const int d0 = threadIdx.x;   // 0..255, handles d0 and d0+256
    const float m0 = (T[0][d0]     + T[1][d0]     + T[2][d0]     + T[3][d0])     * 0.25f;
    const float m1 = (T[0][d0+256] + T[1][d0+256] + T[2][d0+256] + T[3][d0+256]) * 0.25f;
    u16* gr = G + ((size_t)bb*NN + n)*DIM;
    gr[d0]       = f2bits(m0);
    gr[d0 + 256] = f2bits(m1);
}

// ---------- fused s_attn + fuse: wave per row; s in-register, then update ----------
__global__ __launch_bounds__(256)
void fuse2_kernel(const float4* __restrict__ xb, const float4* __restrict__ m1,
                  const u16* __restrict__ ca, const u16* __restrict__ xl,
                  const u16* __restrict__ xg, const float* __restrict__ wsv,
                  const float* __restrict__ bs, float4* __restrict__ xa)
{
    const int wave = threadIdx.x >> 6, lane = threadIdx.x & 63;
    const int row = blockIdx.x * 4 + wave;
    const int b = row >> 10, n = row & 255;
    const u16* xlr = xl + (size_t)row * RED;
    const u16* xgr = xg + ((size_t)b*NN + n) * RED;
    float s = bits2f(xlr[lane])    * wsv[lane]
            + bits2f(xlr[lane+64]) * wsv[lane+64]
            + bits2f(xgr[lane])    * wsv[RED+lane]
            + bits2f(xgr[lane+64]) * wsv[RED+64+lane];
#pragma unroll
    for (int off = 32; off; off >>= 1) s += __shfl_xor(s, off);
    s = 1.f / (1.f + __expf(-(s + bs[0])));
    const u16* car = ca + ((((size_t)b << 8) + n)*DIM);
#pragma unroll
    for (int t = 0; t < 2; ++t) {
        const int dg = lane + t*64;
        const size_t idx = (size_t)row*128 + dg;
        ushort4 cu = *(const ushort4*)(car + dg*4);
        float4 xv = xb[idx], mv = m1[idx], o;
        o.x = xv.x + mv.x * bits2f(cu.x) * s;
        o.y = xv.y + mv.y * bits2f(cu.y) * s;
        o.z = xv.z + mv.z * bits2f(cu.z) * s;
        o.w = xv.w + mv.w * bits2f(cu.w) * s;
        xa[idx] = o;
    }
}

// ---------- host launch ----------
extern "C" void kernel_launch(void* const* d_in, const int* in_sizes, int n_in,
                              void* d_out, int out_size, void* d_ws, size_t ws_size,
                              hipStream_t stream)
{
    const float* x_in  = (const float*)d_in[0];
    const float* ln1_g = (const float*)d_in[1];
    const float* ln1_b = (const float*)d_in[2];
    const float* w_qkv = (const float*)d_in[3];
    const float* w_o   = (const float*)d_in[4];
    const float* b_o   = (const float*)d_in[5];
    const float* ln2_g = (const float*)d_in[6];
    const float* ln2_b = (const float*)d_in[7];
    const float* w1    = (const float*)d_in[8];
    const float* b1    = (const float*)d_in[9];
    const float* w2    = (const float*)d_in[10];
    const float* b2    = (const float*)d_in[11];
    const float* bn_g  = (const float*)d_in[12];
    const float* bn_b  = (const float*)d_in[13];
    const float* wg    = (const float*)d_in[14];
    const float* bg    = (const float*)d_in[15];
    const float* wl    = (const float*)d_in[16];
    const float* bl    = (const float*)d_in[17];
    const float* wc    = (const float*)d_in[18];
    const float* bc    = (const float*)d_in[19];
    const float* wsw   = (const float*)d_in[20];
    const float* bsb   = (const float*)d_in[21];

    char* ws = (char*)d_ws;
    auto alloc = [&](size_t bytes) {
        char* p = ws;
        ws += (bytes + 255) & ~(size_t)255;
        return p;
    };
    float* XA = (float*)alloc(XELEMS * 4);
    float* XB = (float*)alloc(XELEMS * 4);
    float* M1 = (float*)alloc(XELEMS * 4);
    u16*   L  = (u16*)  alloc(XELEMS * 2);
    u16*   Q  = (u16*)  alloc((size_t)ROWS * 3*DIM * 2);
    u16*   H  = (u16*)  alloc((size_t)ROWS * MLPD * 2);
    u16*   G  = (u16*)  alloc((size_t)BB*NN*DIM * 2);
    u16*   G2 = (u16*)  alloc((size_t)BB*NN*RED * 2);
    u16*   XL = (u16*)  alloc((size_t)ROWS*RED * 2);
    u16*   CA = (u16*)  alloc((size_t)BB*NN*DIM * 2);
    // all-layer transposed bf16 weights
    u16* WTqkv = (u16*)alloc((size_t)DEPTH*DIM*3*DIM * 2);
    u16* WTo   = (u16*)alloc((size_t)DEPTH*DIM*DIM * 2);
    u16* WT1   = (u16*)alloc((size_t)DEPTH*DIM*MLPD * 2);
    u16* WT2   = (u16*)alloc((size_t)DEPTH*MLPD*DIM * 2);
    u16* WTl   = (u16*)alloc((size_t)DEPTH*DIM*RED * 2);
    u16* WTg   = (u16*)alloc((size_t)DEPTH*DIM*RED * 2);
    u16* WTc   = (u16*)alloc((size_t)DEPTH*RED*DIM * 2);

    // ---- all weight transposes upfront, batched over depth ----
    wtrans_all<<<dim3(48,16,DEPTH), 256, 0, stream>>>(w_qkv, WTqkv, DIM, 3*DIM);
    wtrans_all<<<dim3(16,16,DEPTH), 256, 0, stream>>>(w_o,   WTo,   DIM, DIM);
    wtrans_all<<<dim3(64,16,DEPTH), 256, 0, stream>>>(w1,    WT1,   DIM, MLPD);
    wtrans_all<<<dim3(16,64,DEPTH), 256, 0, stream>>>(w2,    WT2,   MLPD, DIM);
    wtrans_all<<<dim3(4,16,DEPTH),  256, 0, stream>>>(wl,    WTl,   DIM, RED);
    wtrans_all<<<dim3(4,16,DEPTH),  256, 0, stream>>>(wg,    WTg,   DIM, RED);
    wtrans_all<<<dim3(16,4,DEPTH),  256, 0, stream>>>(wc,    WTc,   RED, DIM);

    for (int l = 0; l < DEPTH; ++l) {
        const float* Xres = l ? (const float*)XA : x_in;   // layer-0 reads input directly
        // ---- attention block ----
        ln_kernel<<<ROWS/4, 256, 0, stream>>>(Xres, ln1_g + l*DIM, ln1_b + l*DIM, L, ROWS);
        gemm_db<64,64,64,2,2><<<dim3(128,24), 256, 0, stream>>>(
            L, WTqkv + (size_t)l*DIM*3*DIM, nullptr, nullptr, Q, ROWS, 3*DIM, DIM, 0, 0);
        attn_mfma<<<BB*PP*HEADS*2, 256, 0, stream>>>(Q, L);
        gemm_db<64,64,64,2,2><<<dim3(128,8), 256, 0, stream>>>(
            L, WTo + (size_t)l*DIM*DIM, b_o + l*DIM, Xres, XB, ROWS, DIM, DIM, 0, 1);

        // ---- MLP ----
        ln_kernel<<<ROWS/4, 256, 0, stream>>>(XB, ln2_g + l*DIM, ln2_b + l*DIM, Q, ROWS);
        gemm_db<64,64,64,2,2><<<dim3(128,32), 256, 0, stream>>>(
            Q, WT1 + (size_t)l*DIM*MLPD, b1 + l*MLPD, nullptr, H, ROWS, MLPD, DIM, 1, 0);
        gemm_db<64,64,64,2,2><<<dim3(128,8), 256, 0, stream>>>(
            H, WT2 + (size_t)l*MLPD*DIM, b2 + l*DIM, nullptr, M1, ROWS, DIM, MLPD, 0, 1);

        // ---- BiAttn ----
        lnmean_kernel<<<BB*NN, 256, 0, stream>>>(M1, bn_g + l*DIM, bn_b + l*DIM, L, G);
        gemm_db<64,64,64,2,2><<<dim3(32,2), 256, 0, stream>>>(
            G, WTg + (size_t)l*DIM*RED, bg + l*RED, nullptr, G2, BB*NN, RED, DIM, 1, 0);
        gemm_db<64,64,64,2,2><<<dim3(128,2), 256, 0, stream>>>(
            L, WTl + (size_t)l*DIM*RED, bl + l*RED, nullptr, XL, ROWS, RED, DIM, 1, 0);
        gemm_db<64,64,64,2,2><<<dim3(32,8), 256, 0, stream>>>(
            G2, WTc + (size_t)l*RED*DIM, bc + l*DIM, nullptr, CA, BB*NN, DIM, RED, 2, 0);
        // fused s_attn + gating + residual; last layer writes d_out directly
        fuse2_kernel<<<ROWS/4, 256, 0, stream>>>((const float4*)XB, (const float4*)M1,
                                                 CA, XL, G2, wsw + (size_t)l*2*RED, bsb + l,
                                                 (l == DEPTH-1) ? (float4*)d_out
                                                                : (float4*)XA);
    }
}

// Round 9
// 904.013 us; speedup vs baseline: 1.4277x; 1.0090x over previous
//
#include <hip/hip_runtime.h>
#include <hip/hip_bf16.h>
#include <math.h>

typedef __hip_bfloat16 bf16;
typedef unsigned short u16;
typedef __bf16 bf16x8 __attribute__((ext_vector_type(8)));
typedef float f32x4 __attribute__((ext_vector_type(4)));

// ---------- helpers ----------
__device__ __forceinline__ float b2f(bf16 v) { return __bfloat162float(v); }
__device__ __forceinline__ bf16 f2b(float v) { return __float2bfloat16(v); }
__device__ __forceinline__ float bits2f(unsigned int u) {
    union { unsigned int i; float f; } w; w.i = u << 16; return w.f;
}
__device__ __forceinline__ u16 f2bits(float v) {
    union { bf16 h; u16 u; } w; w.h = __float2bfloat16(v); return w.u;
}
__device__ __forceinline__ void async16(void* lds, const void* g) {
    __builtin_amdgcn_global_load_lds(
        (const __attribute__((address_space(1))) unsigned int*)g,
        (__attribute__((address_space(3))) unsigned int*)lds, 16, 0, 0);
}

#define DEPTH 4
#define HEADS 8
#define DHEAD 64
#define DIM 512
#define MLPD 2048
#define RED 128
#define BB 8
#define PP 4
#define NN 256
#define ROWS (BB*PP*NN)          // 8192 tokens
#define XELEMS ((size_t)ROWS*DIM) // 4194304

// ---------- batched weight transpose+cast: W fp32 [D][K][N] -> WT bf16 [D][N][K] ----------
__global__ __launch_bounds__(256)
void wtrans_all(const float* __restrict__ W, u16* __restrict__ WT, int K, int N)
{
    __shared__ float T[32][33];
    const int l = blockIdx.z;
    W  += (size_t)l * K * N;
    WT += (size_t)l * N * K;
    const int tx = threadIdx.x & 31, ty = threadIdx.x >> 5; // ty 0..7
    const int n0 = blockIdx.x * 32, k0 = blockIdx.y * 32;
#pragma unroll
    for (int r = 0; r < 4; ++r)
        T[ty + r*8][tx] = W[(size_t)(k0 + ty + r*8) * N + n0 + tx];
    __syncthreads();
#pragma unroll
    for (int r = 0; r < 4; ++r)
        WT[(size_t)(n0 + ty + r*8) * K + k0 + tx] = f2bits(T[tx][ty + r*8]);
}

// ---------- double-buffered MFMA GEMM (2-phase): C = act(A @ WT^T + bias) [+res]
template<int BM, int BN, int BK, int WROWS, int WCOLS>
__global__ __launch_bounds__(256)
void gemm_db(const u16* __restrict__ A, const u16* __restrict__ WT,
             const float* __restrict__ bias, const float* __restrict__ res,
             void* __restrict__ Cv, int M, int N, int K, int act, int outf32)
{
    constexpr int KG  = BK/8;        // 16B k-groups per row
    constexpr int RPC = 512/BK;      // rows per 1KB staging chunk
    constexpr int NCA = BM*BK/512;   // A chunks
    constexpr int NCB = BN*BK/512;   // B chunks
    constexpr int CPT = (NCA+NCB)/4; // chunks per wave
    constexpr int WM = BM/WROWS, WN = BN/WCOLS;
    constexpr int AM = WM/16, AN = WN/16, KB = BK/32;

    __shared__ u16 As[2][BM*BK];
    __shared__ u16 Bs[2][BN*BK];
    const int tid = threadIdx.x, wave = tid >> 6, lane = tid & 63;
    const int bm = blockIdx.x * BM;
    const int bn = blockIdx.y * BN;
    const int wm = (wave / WCOLS) * WM, wn = (wave % WCOLS) * WN;
    const int lr = lane & 15, quad = lane >> 4;

    const int rowc = lane / KG;
    const int kgs  = ((lane & (KG-1)) ^ (KG == 4 ? ((rowc >> 1) & 3) : (rowc & 7))) * 8;

    auto stage = [&](int buf, int k0) {
#pragma unroll
        for (int t = 0; t < CPT; ++t) {
            const int c = wave*CPT + t;
            if (c < NCA)
                async16(&As[buf][c*512], A  + (size_t)(bm + c*RPC + rowc) * K + k0 + kgs);
            else
                async16(&Bs[buf][(c-NCA)*512], WT + (size_t)(bn + (c-NCA)*RPC + rowc) * K + k0 + kgs);
        }
    };

    f32x4 acc[AM][AN] = {};

    stage(0, 0);
    __syncthreads();

    const int NK = K / BK;
    for (int ki = 0; ki < NK; ++ki) {
        const int cur = ki & 1;
        if (ki + 1 < NK) stage(cur ^ 1, (ki + 1) * BK);

        bf16x8 af[AM][KB], bv[AN][KB];
#pragma unroll
        for (int i = 0; i < AM; ++i) {
            const int rA = wm + i*16 + lr;
            const int sw = (KG == 4 ? (((rA & 15) >> 1) & 3) : (rA & 7));
#pragma unroll
            for (int kb = 0; kb < KB; ++kb)
                af[i][kb] = *(const bf16x8*)(As[cur] + rA*BK + (((kb*4 + quad) ^ sw) * 8));
        }
#pragma unroll
        for (int j = 0; j < AN; ++j) {
            const int rB = wn + j*16 + lr;
            const int sw = (KG == 4 ? (((rB & 15) >> 1) & 3) : (rB & 7));
#pragma unroll
            for (int kb = 0; kb < KB; ++kb)
                bv[j][kb] = *(const bf16x8*)(Bs[cur] + rB*BK + (((kb*4 + quad) ^ sw) * 8));
        }
#pragma unroll
        for (int i = 0; i < AM; ++i)
#pragma unroll
            for (int j = 0; j < AN; ++j)
#pragma unroll
                for (int kb = 0; kb < KB; ++kb)
                    acc[i][j] = __builtin_amdgcn_mfma_f32_16x16x32_bf16(
                        af[i][kb], bv[j][kb], acc[i][j], 0, 0, 0);
        __syncthreads();
    }

#pragma unroll
    for (int i = 0; i < AM; ++i) {
        const int rowb = bm + wm + i*16 + quad*4;
#pragma unroll
        for (int j = 0; j < AN; ++j) {
            const int col = bn + wn + j*16 + lr;
            const float bvs = bias ? bias[col] : 0.f;
#pragma unroll
            for (int r = 0; r < 4; ++r) {
                float v = acc[i][j][r] + bvs;
                if (act == 1) v = 0.5f * v * (1.0f + erff(v * 0.70710678118f));
                else if (act == 2) v = 1.0f / (1.0f + __expf(-v));
                const size_t idx = (size_t)(rowb + r) * N + col;
                if (res) v += res[idx];
                if (outf32) ((float*)Cv)[idx] = v;
                else        ((u16*)Cv)[idx] = f2bits(v);
            }
        }
    }
}

// ---------- MFMA flash attention, 4-way split-Q: one block per (b,p,h,qquarter) ----------
// Grid 2048 -> up to 5 blocks/CU (27 KB LDS): independent barrier domains overlap
// staging with MFMA across blocks. 4 waves x 16 q-rows each.
__global__ __launch_bounds__(256)
void attn_mfma(const u16* __restrict__ qkv, u16* __restrict__ out)
{
    __shared__ u16 Kt[64*72];
    __shared__ u16 Vt[64*72];
    __shared__ u16 Pw[4][16*72];
    const int tid = threadIdx.x;
    const int wave = tid >> 6, lane = tid & 63;
    const int lr = lane & 15, quad = lane >> 4;
    const int bp = blockIdx.x >> 5;          // (b,p)
    const int h  = (blockIdx.x >> 2) & 7;    // head
    const int qq = blockIdx.x & 3;           // query quarter
    const u16* base = qkv + (size_t)bp * NN * (3*DIM);
    const int qo = h*DHEAD, ko = DIM + h*DHEAD, vo = 2*DIM + h*DHEAD;
    const int m0 = qq*64 + wave*16;

    bf16x8 qf[2];
#pragma unroll
    for (int kb = 0; kb < 2; ++kb)
        qf[kb] = *(const bf16x8*)(base + (size_t)(m0 + lr)*(3*DIM) + qo + kb*32 + quad*8);

    f32x4 o[4] = {};
    float mrow[4], lrow[4];
#pragma unroll
    for (int r = 0; r < 4; ++r) { mrow[r] = -1e30f; lrow[r] = 0.f; }

    const int sr = tid >> 3, sc = tid & 7;

    for (int t = 0; t < 4; ++t) {
        __syncthreads();
#pragma unroll
        for (int half = 0; half < 2; ++half) {
            const int key = half*32 + sr;
            const u16* krow = base + (size_t)(t*64 + key)*(3*DIM);
            uint4 kv = *(const uint4*)(krow + ko + sc*8);
            *(uint4*)(Kt + key*72 + sc*8) = kv;
            uint4 vv = *(const uint4*)(krow + vo + sc*8);
            const int d0 = sc*8;
            Vt[(d0+0)*72 + key] = (u16)(vv.x & 0xffffu);
            Vt[(d0+1)*72 + key] = (u16)(vv.x >> 16);
            Vt[(d0+2)*72 + key] = (u16)(vv.y & 0xffffu);
            Vt[(d0+3)*72 + key] = (u16)(vv.y >> 16);
            Vt[(d0+4)*72 + key] = (u16)(vv.z & 0xffffu);
            Vt[(d0+5)*72 + key] = (u16)(vv.z >> 16);
            Vt[(d0+6)*72 + key] = (u16)(vv.w & 0xffffu);
            Vt[(d0+7)*72 + key] = (u16)(vv.w >> 16);
        }
        __syncthreads();

        f32x4 s[4] = {};
        bf16x8 kf[4][2];
#pragma unroll
        for (int j = 0; j < 4; ++j)
#pragma unroll
            for (int kb = 0; kb < 2; ++kb)
                kf[j][kb] = *(const bf16x8*)(Kt + (j*16 + lr)*72 + kb*32 + quad*8);
#pragma unroll
        for (int j = 0; j < 4; ++j)
#pragma unroll
            for (int kb = 0; kb < 2; ++kb)
                s[j] = __builtin_amdgcn_mfma_f32_16x16x32_bf16(
                    qf[kb], kf[j][kb], s[j], 0, 0, 0);

        float alpha[4];
#pragma unroll
        for (int r = 0; r < 4; ++r) {
#pragma unroll
            for (int j = 0; j < 4; ++j) s[j][r] *= 0.125f;
            float mt = fmaxf(fmaxf(s[0][r], s[1][r]), fmaxf(s[2][r], s[3][r]));
#pragma unroll
            for (int off = 1; off <= 8; off <<= 1) mt = fmaxf(mt, __shfl_xor(mt, off));
            const float mn = fmaxf(mrow[r], mt);
            alpha[r] = __expf(mrow[r] - mn);
            mrow[r] = mn;
            float ssum = 0.f;
#pragma unroll
            for (int j = 0; j < 4; ++j) {
                const float p = __expf(s[j][r] - mn);
                s[j][r] = p; ssum += p;
            }
#pragma unroll
            for (int off = 1; off <= 8; off <<= 1) ssum += __shfl_xor(ssum, off);
            lrow[r] = lrow[r]*alpha[r] + ssum;
        }

#pragma unroll
        for (int j = 0; j < 4; ++j)
#pragma unroll
            for (int r = 0; r < 4; ++r)
                Pw[wave][(quad*4 + r)*72 + j*16 + lr] = f2bits(s[j][r]);
        __syncthreads();

#pragma unroll
        for (int jd = 0; jd < 4; ++jd)
#pragma unroll
            for (int r = 0; r < 4; ++r)
                o[jd][r] *= alpha[r];

        bf16x8 af[2], bv[4][2];
#pragma unroll
        for (int kb = 0; kb < 2; ++kb)
            af[kb] = *(const bf16x8*)(Pw[wave] + lr*72 + kb*32 + quad*8);
#pragma unroll
        for (int jd = 0; jd < 4; ++jd)
#pragma unroll
            for (int kb = 0; kb < 2; ++kb)
                bv[jd][kb] = *(const bf16x8*)(Vt + (jd*16 + lr)*72 + kb*32 + quad*8);
#pragma unroll
        for (int jd = 0; jd < 4; ++jd)
#pragma unroll
            for (int kb = 0; kb < 2; ++kb)
                o[jd] = __builtin_amdgcn_mfma_f32_16x16x32_bf16(
                    af[kb], bv[jd][kb], o[jd], 0, 0, 0);
    }

#pragma unroll
    for (int r = 0; r < 4; ++r) {
        const float inv = 1.0f / lrow[r];
        const size_t rowg = (size_t)bp*NN + m0 + quad*4 + r;
#pragma unroll
        for (int jd = 0; jd < 4; ++jd)
            out[rowg*DIM + h*DHEAD + jd*16 + lr] = f2bits(o[jd][r] * inv);
    }
}

// ---------- LayerNorm over DIM=512, fp32 in, bf16 out; one wave per row; float4 ----------
__global__ __launch_bounds__(256)
void ln_kernel(const float* __restrict__ x, const float* __restrict__ g,
               const float* __restrict__ b, u16* __restrict__ y, int rows)
{
    const int wave = threadIdx.x >> 6, lane = threadIdx.x & 63;
    const int row = blockIdx.x * 4 + wave;
    if (row >= rows) return;
    const float4* xr = (const float4*)(x + (size_t)row * DIM);
    float4 v0 = xr[lane], v1 = xr[lane + 64];
    float s  = v0.x+v0.y+v0.z+v0.w + v1.x+v1.y+v1.z+v1.w;
    float s2 = v0.x*v0.x+v0.y*v0.y+v0.z*v0.z+v0.w*v0.w
             + v1.x*v1.x+v1.y*v1.y+v1.z*v1.z+v1.w*v1.w;
#pragma unroll
    for (int off = 32; off; off >>= 1) { s += __shfl_xor(s, off); s2 += __shfl_xor(s2, off); }
    const float mean = s * (1.f/512.f);
    const float var  = s2 * (1.f/512.f) - mean*mean;
    const float rstd = rsqrtf(var + 1e-5f);
    const float4* gp = (const float4*)g; const float4* bp = (const float4*)b;
    float4 g0 = gp[lane], g1 = gp[lane+64], b0 = bp[lane], b1 = bp[lane+64];
    ushort4 o0, o1;
    o0.x = f2bits((v0.x-mean)*rstd*g0.x + b0.x);
    o0.y = f2bits((v0.y-mean)*rstd*g0.y + b0.y);
    o0.z = f2bits((v0.z-mean)*rstd*g0.z + b0.z);
    o0.w = f2bits((v0.w-mean)*rstd*g0.w + b0.w);
    o1.x = f2bits((v1.x-mean)*rstd*g1.x + b1.x);
    o1.y = f2bits((v1.y-mean)*rstd*g1.y + b1.y);
    o1.z = f2bits((v1.z-mean)*rstd*g1.z + b1.z);
    o1.w = f2bits((v1.w-mean)*rstd*g1.w + b1.w);
    ushort4* yr = (ushort4*)(y + (size_t)row * DIM);
    yr[lane] = o0; yr[lane+64] = o1;
}

// ---------- fused BiAttn LN + mean over P: block=(b,n), wave p=0..3 ----------
__global__ __launch_bounds__(256)
void lnmean_kernel(const float* __restrict__ x, const float* __restrict__ g,
                   const float* __restrict__ b, u16* __restrict__ y,
                   u16* __restrict__ G)
{
    __shared__ float T[4][512];
    const int wave = threadIdx.x >> 6, lane = threadIdx.x & 63;
    const int bb = blockIdx.x >> 8, n = blockIdx.x & 255;
    const int row = (bb*PP + wave)*NN + n;
    const float4* xr = (const float4*)(x + (size_t)row * DIM);
    float4 v0 = xr[lane], v1 = xr[lane + 64];
    float s  = v0.x+v0.y+v0.z+v0.w + v1.x+v1.y+v1.z+v1.w;
    float s2 = v0.x*v0.x+v0.y*v0.y+v0.z*v0.z+v0.w*v0.w
             + v1.x*v1.x+v1.y*v1.y+v1.z*v1.z+v1.w*v1.w;
#pragma unroll
    for (int off = 32; off; off >>= 1) { s += __shfl_xor(s, off); s2 += __shfl_xor(s2, off); }
    const float mean = s * (1.f/512.f);
    const float var  = s2 * (1.f/512.f) - mean*mean;
    const float rstd = rsqrtf(var + 1e-5f);
    const float4* gp = (const float4*)g; const float4* bp = (const float4*)b;
    float4 g0 = gp[lane], g1 = gp[lane+64], b0 = bp[lane], b1 = bp[lane+64];
    float4 y0, y1;
    y0.x = (v0.x-mean)*rstd*g0.x + b0.x;
    y0.y = (v0.y-mean)*rstd*g0.y + b0.y;
    y0.z = (v0.z-mean)*rstd*g0.z + b0.z;
    y0.w = (v0.w-mean)*rstd*g0.w + b0.w;
    y1.x = (v1.x-mean)*rstd*g1.x + b1.x;
    y1.y = (v1.y-mean)*rstd*g1.y + b1.y;
    y1.z = (v1.z-mean)*rstd*g1.z + b1.z;
    y1.w = (v1.w-mean)*rstd*g1.w + b1.w;
    ushort4 o0, o1;
    o0.x = f2bits(y0.x); o0.y = f2bits(y0.y); o0.z = f2bits(y0.z); o0.w = f2bits(y0.w);
    o1.x = f2bits(y1.x); o1.y = f2bits(y1.y); o1.z = f2bits(y1.z); o1.w = f2bits(y1.w);
    ushort4* yr = (ushort4*)(y + (size_t)row * DIM);
    yr[lane] = o0; yr[lane+64] = o1;
    *(float4*)&T[wave][lane*4]       = y0;
    *(float4*)&T[wave][256 + lane*4] = y1;
    __syncthreads();
    const int d0 = threadIdx.x;   // 0..255, handles d0 and d0+256
    const float m0 = (T[0][d0]     + T[1][d0]     + T[2][d0]     + T[3][d0])     * 0.25f;
    const float m1 = (T[0][d0+256] + T[1][d0+256] + T[2][d0+256] + T[3][d0+256]) * 0.25f;
    u16* gr = G + ((size_t)bb*NN + n)*DIM;
    gr[d0]       = f2bits(m0);
    gr[d0 + 256] = f2bits(m1);
}

// ---------- fused s_attn + fuse: wave per row; s in-register, then update ----------
__global__ __launch_bounds__(256)
void fuse2_kernel(const float4* __restrict__ xb, const float4* __restrict__ m1,
                  const u16* __restrict__ ca, const u16* __restrict__ xl,
                  const u16* __restrict__ xg, const float* __restrict__ wsv,
                  const float* __restrict__ bs, float4* __restrict__ xa)
{
    const int wave = threadIdx.x >> 6, lane = threadIdx.x & 63;
    const int row = blockIdx.x * 4 + wave;
    const int b = row >> 10, n = row & 255;
    const u16* xlr = xl + (size_t)row * RED;
    const u16* xgr = xg + ((size_t)b*NN + n) * RED;
    float s = bits2f(xlr[lane])    * wsv[lane]
            + bits2f(xlr[lane+64]) * wsv[lane+64]
            + bits2f(xgr[lane])    * wsv[RED+lane]
            + bits2f(xgr[lane+64]) * wsv[RED+64+lane];
#pragma unroll
    for (int off = 32; off; off >>= 1) s += __shfl_xor(s, off);
    s = 1.f / (1.f + __expf(-(s + bs[0])));
    const u16* car = ca + ((((size_t)b << 8) + n)*DIM);
#pragma unroll
    for (int t = 0; t < 2; ++t) {
        const int dg = lane + t*64;
        const size_t idx = (size_t)row*128 + dg;
        ushort4 cu = *(const ushort4*)(car + dg*4);
        float4 xv = xb[idx], mv = m1[idx], o;
        o.x = xv.x + mv.x * bits2f(cu.x) * s;
        o.y = xv.y + mv.y * bits2f(cu.y) * s;
        o.z = xv.z + mv.z * bits2f(cu.z) * s;
        o.w = xv.w + mv.w * bits2f(cu.w) * s;
        xa[idx] = o;
    }
}

// ---------- host launch ----------
extern "C" void kernel_launch(void* const* d_in, const int* in_sizes, int n_in,
                              void* d_out, int out_size, void* d_ws, size_t ws_size,
                              hipStream_t stream)
{
    const float* x_in  = (const float*)d_in[0];
    const float* ln1_g = (const float*)d_in[1];
    const float* ln1_b = (const float*)d_in[2];
    const float* w_qkv = (const float*)d_in[3];
    const float* w_o   = (const float*)d_in[4];
    const float* b_o   = (const float*)d_in[5];
    const float* ln2_g = (const float*)d_in[6];
    const float* ln2_b = (const float*)d_in[7];
    const float* w1    = (const float*)d_in[8];
    const float* b1    = (const float*)d_in[9];
    const float* w2    = (const float*)d_in[10];
    const float* b2    = (const float*)d_in[11];
    const float* bn_g  = (const float*)d_in[12];
    const float* bn_b  = (const float*)d_in[13];
    const float* wg    = (const float*)d_in[14];
    const float* bg    = (const float*)d_in[15];
    const float* wl    = (const float*)d_in[16];
    const float* bl    = (const float*)d_in[17];
    const float* wc    = (const float*)d_in[18];
    const float* bc    = (const float*)d_in[19];
    const float* wsw   = (const float*)d_in[20];
    const float* bsb   = (const float*)d_in[21];

    char* ws = (char*)d_ws;
    auto alloc = [&](size_t bytes) {
        char* p = ws;
        ws += (bytes + 255) & ~(size_t)255;
        return p;
    };
    float* XA = (float*)alloc(XELEMS * 4);
    float* XB = (float*)alloc(XELEMS * 4);
    float* M1 = (float*)alloc(XELEMS * 4);
    u16*   L  = (u16*)  alloc(XELEMS * 2);
    u16*   Q  = (u16*)  alloc((size_t)ROWS * 3*DIM * 2);
    u16*   H  = (u16*)  alloc((size_t)ROWS * MLPD * 2);
    u16*   G  = (u16*)  alloc((size_t)BB*NN*DIM * 2);
    u16*   G2 = (u16*)  alloc((size_t)BB*NN*RED * 2);
    u16*   XL = (u16*)  alloc((size_t)ROWS*RED * 2);
    u16*   CA = (u16*)  alloc((size_t)BB*NN*DIM * 2);
    // all-layer transposed bf16 weights
    u16* WTqkv = (u16*)alloc((size_t)DEPTH*DIM*3*DIM * 2);
    u16* WTo   = (u16*)alloc((size_t)DEPTH*DIM*DIM * 2);
    u16* WT1   = (u16*)alloc((size_t)DEPTH*DIM*MLPD * 2);
    u16* WT2   = (u16*)alloc((size_t)DEPTH*MLPD*DIM * 2);
    u16* WTl   = (u16*)alloc((size_t)DEPTH*DIM*RED * 2);
    u16* WTg   = (u16*)alloc((size_t)DEPTH*DIM*RED * 2);
    u16* WTc   = (u16*)alloc((size_t)DEPTH*RED*DIM * 2);

    // ---- all weight transposes upfront, batched over depth ----
    wtrans_all<<<dim3(48,16,DEPTH), 256, 0, stream>>>(w_qkv, WTqkv, DIM, 3*DIM);
    wtrans_all<<<dim3(16,16,DEPTH), 256, 0, stream>>>(w_o,   WTo,   DIM, DIM);
    wtrans_all<<<dim3(64,16,DEPTH), 256, 0, stream>>>(w1,    WT1,   DIM, MLPD);
    wtrans_all<<<dim3(16,64,DEPTH), 256, 0, stream>>>(w2,    WT2,   MLPD, DIM);
    wtrans_all<<<dim3(4,16,DEPTH),  256, 0, stream>>>(wl,    WTl,   DIM, RED);
    wtrans_all<<<dim3(4,16,DEPTH),  256, 0, stream>>>(wg,    WTg,   DIM, RED);
    wtrans_all<<<dim3(16,4,DEPTH),  256, 0, stream>>>(wc,    WTc,   RED, DIM);

    for (int l = 0; l < DEPTH; ++l) {
        const float* Xres = l ? (const float*)XA : x_in;   // layer-0 reads input directly
        // ---- attention block ----
        ln_kernel<<<ROWS/4, 256, 0, stream>>>(Xres, ln1_g + l*DIM, ln1_b + l*DIM, L, ROWS);
        gemm_db<64,64,64,2,2><<<dim3(128,24), 256, 0, stream>>>(
            L, WTqkv + (size_t)l*DIM*3*DIM, nullptr, nullptr, Q, ROWS, 3*DIM, DIM, 0, 0);
        attn_mfma<<<BB*PP*HEADS*4, 256, 0, stream>>>(Q, L);
        gemm_db<64,64,64,2,2><<<dim3(128,8), 256, 0, stream>>>(
            L, WTo + (size_t)l*DIM*DIM, b_o + l*DIM, Xres, XB, ROWS, DIM, DIM, 0, 1);

        // ---- MLP ----
        ln_kernel<<<ROWS/4, 256, 0, stream>>>(XB, ln2_g + l*DIM, ln2_b + l*DIM, Q, ROWS);
        gemm_db<64,64,32,2,2><<<dim3(128,32), 256, 0, stream>>>(
            Q, WT1 + (size_t)l*DIM*MLPD, b1 + l*MLPD, nullptr, H, ROWS, MLPD, DIM, 1, 0);
        gemm_db<64,64,64,2,2><<<dim3(128,8), 256, 0, stream>>>(
            H, WT2 + (size_t)l*MLPD*DIM, b2 + l*DIM, nullptr, M1, ROWS, DIM, MLPD, 0, 1);

        // ---- BiAttn ----
        lnmean_kernel<<<BB*NN, 256, 0, stream>>>(M1, bn_g + l*DIM, bn_b + l*DIM, L, G);
        gemm_db<64,64,64,2,2><<<dim3(32,2), 256, 0, stream>>>(
            G, WTg + (size_t)l*DIM*RED, bg + l*RED, nullptr, G2, BB*NN, RED, DIM, 1, 0);
        gemm_db<64,64,64,2,2><<<dim3(128,2), 256, 0, stream>>>(
            L, WTl + (size_t)l*DIM*RED, bl + l*RED, nullptr, XL, ROWS, RED, DIM, 1, 0);
        gemm_db<64,64,64,2,2><<<dim3(32,8), 256, 0, stream>>>(
            G2, WTc + (size_t)l*RED*DIM, bc + l*DIM, nullptr, CA, BB*NN, DIM, RED, 2, 0);
        // fused s_attn + gating + residual; last layer writes d_out directly
        fuse2_kernel<<<ROWS/4, 256, 0, stream>>>((const float4*)XB, (const float4*)M1,
                                                 CA, XL, G2, wsw + (size_t)l*2*RED, bsb + l,
                                                 (l == DEPTH-1) ? (float4*)d_out
                                                                : (float4*)XA);
    }
}

// Round 10
// 836.272 us; speedup vs baseline: 1.5434x; 1.0810x over previous
//
#include <hip/hip_runtime.h>
#include <hip/hip_bf16.h>
#include <math.h>

typedef __hip_bfloat16 bf16;
typedef unsigned short u16;
typedef __bf16 bf16x8 __attribute__((ext_vector_type(8)));
typedef float f32x4 __attribute__((ext_vector_type(4)));

// ---------- helpers ----------
__device__ __forceinline__ float b2f(bf16 v) { return __bfloat162float(v); }
__device__ __forceinline__ bf16 f2b(float v) { return __float2bfloat16(v); }
__device__ __forceinline__ float bits2f(unsigned int u) {
    union { unsigned int i; float f; } w; w.i = u << 16; return w.f;
}
__device__ __forceinline__ u16 f2bits(float v) {
    union { bf16 h; u16 u; } w; w.h = __float2bfloat16(v); return w.u;
}
__device__ __forceinline__ void async16(void* lds, const void* g) {
    __builtin_amdgcn_global_load_lds(
        (const __attribute__((address_space(1))) unsigned int*)g,
        (__attribute__((address_space(3))) unsigned int*)lds, 16, 0, 0);
}

#define DEPTH 4
#define HEADS 8
#define DHEAD 64
#define DIM 512
#define MLPD 2048
#define RED 128
#define BB 8
#define PP 4
#define NN 256
#define ROWS (BB*PP*NN)          // 8192 tokens
#define XELEMS ((size_t)ROWS*DIM) // 4194304

// ---------- fused batched weight transpose+cast, ALL 7 weights in one launch ----------
// W fp32 [D][K][N] -> WT bf16 [D][N][K]. blockIdx.x segments: qkv|wo|w1|w2|wl|wg|wc.
__global__ __launch_bounds__(256)
void wtrans_fused(const float* __restrict__ Wqkv, u16* __restrict__ Tqkv,
                  const float* __restrict__ Wo,   u16* __restrict__ To,
                  const float* __restrict__ W1,   u16* __restrict__ T1,
                  const float* __restrict__ W2,   u16* __restrict__ T2,
                  const float* __restrict__ Wl,   u16* __restrict__ Tl,
                  const float* __restrict__ Wg,   u16* __restrict__ Tg,
                  const float* __restrict__ Wc,   u16* __restrict__ Tc)
{
    __shared__ float T[32][33];
    const int x = blockIdx.x, l = blockIdx.z;
    const float* W; u16* WT; int K, N, nx, local;
    if      (x < 768)  { W=Wqkv; WT=Tqkv; K=512;  N=1536; nx=48; local=x; }
    else if (x < 1024) { W=Wo;   WT=To;   K=512;  N=512;  nx=16; local=x-768; }
    else if (x < 2048) { W=W1;   WT=T1;   K=512;  N=2048; nx=64; local=x-1024; }
    else if (x < 3072) { W=W2;   WT=T2;   K=2048; N=512;  nx=16; local=x-2048; }
    else if (x < 3136) { W=Wl;   WT=Tl;   K=512;  N=128;  nx=4;  local=x-3072; }
    else if (x < 3200) { W=Wg;   WT=Tg;   K=512;  N=128;  nx=4;  local=x-3136; }
    else               { W=Wc;   WT=Tc;   K=128;  N=512;  nx=16; local=x-3200; }
    W  += (size_t)l * K * N;
    WT += (size_t)l * N * K;
    const int n0 = (local % nx) * 32, k0 = (local / nx) * 32;
    const int tx = threadIdx.x & 31, ty = threadIdx.x >> 5;
#pragma unroll
    for (int r = 0; r < 4; ++r)
        T[ty + r*8][tx] = W[(size_t)(k0 + ty + r*8) * N + n0 + tx];
    __syncthreads();
#pragma unroll
    for (int r = 0; r < 4; ++r)
        WT[(size_t)(n0 + ty + r*8) * K + k0 + tx] = f2bits(T[tx][ty + r*8]);
}

// ---------- double-buffered MFMA GEMM (2-phase): C = act(A @ WT^T + bias) [+res]
template<int BM, int BN, int BK, int WROWS, int WCOLS>
__global__ __launch_bounds__(256)
void gemm_db(const u16* __restrict__ A, const u16* __restrict__ WT,
             const float* __restrict__ bias, const float* __restrict__ res,
             void* __restrict__ Cv, int M, int N, int K, int act, int outf32)
{
    constexpr int KG  = BK/8;        // 16B k-groups per row
    constexpr int RPC = 512/BK;      // rows per 1KB staging chunk
    constexpr int NCA = BM*BK/512;   // A chunks
    constexpr int NCB = BN*BK/512;   // B chunks
    constexpr int CPT = (NCA+NCB)/4; // chunks per wave
    constexpr int WM = BM/WROWS, WN = BN/WCOLS;
    constexpr int AM = WM/16, AN = WN/16, KB = BK/32;

    __shared__ u16 As[2][BM*BK];
    __shared__ u16 Bs[2][BN*BK];
    const int tid = threadIdx.x, wave = tid >> 6, lane = tid & 63;
    const int bm = blockIdx.x * BM;
    const int bn = blockIdx.y * BN;
    const int wm = (wave / WCOLS) * WM, wn = (wave % WCOLS) * WN;
    const int lr = lane & 15, quad = lane >> 4;

    const int rowc = lane / KG;
    const int kgs  = ((lane & (KG-1)) ^ (KG == 4 ? ((rowc >> 1) & 3) : (rowc & 7))) * 8;

    auto stage = [&](int buf, int k0) {
#pragma unroll
        for (int t = 0; t < CPT; ++t) {
            const int c = wave*CPT + t;
            if (c < NCA)
                async16(&As[buf][c*512], A  + (size_t)(bm + c*RPC + rowc) * K + k0 + kgs);
            else
                async16(&Bs[buf][(c-NCA)*512], WT + (size_t)(bn + (c-NCA)*RPC + rowc) * K + k0 + kgs);
        }
    };

    f32x4 acc[AM][AN] = {};

    stage(0, 0);
    __syncthreads();

    const int NK = K / BK;
    for (int ki = 0; ki < NK; ++ki) {
        const int cur = ki & 1;
        if (ki + 1 < NK) stage(cur ^ 1, (ki + 1) * BK);

        bf16x8 af[AM][KB], bv[AN][KB];
#pragma unroll
        for (int i = 0; i < AM; ++i) {
            const int rA = wm + i*16 + lr;
            const int sw = (KG == 4 ? (((rA & 15) >> 1) & 3) : (rA & 7));
#pragma unroll
            for (int kb = 0; kb < KB; ++kb)
                af[i][kb] = *(const bf16x8*)(As[cur] + rA*BK + (((kb*4 + quad) ^ sw) * 8));
        }
#pragma unroll
        for (int j = 0; j < AN; ++j) {
            const int rB = wn + j*16 + lr;
            const int sw = (KG == 4 ? (((rB & 15) >> 1) & 3) : (rB & 7));
#pragma unroll
            for (int kb = 0; kb < KB; ++kb)
                bv[j][kb] = *(const bf16x8*)(Bs[cur] + rB*BK + (((kb*4 + quad) ^ sw) * 8));
        }
#pragma unroll
        for (int i = 0; i < AM; ++i)
#pragma unroll
            for (int j = 0; j < AN; ++j)
#pragma unroll
                for (int kb = 0; kb < KB; ++kb)
                    acc[i][j] = __builtin_amdgcn_mfma_f32_16x16x32_bf16(
                        af[i][kb], bv[j][kb], acc[i][j], 0, 0, 0);
        __syncthreads();
    }

#pragma unroll
    for (int i = 0; i < AM; ++i) {
        const int rowb = bm + wm + i*16 + quad*4;
#pragma unroll
        for (int j = 0; j < AN; ++j) {
            const int col = bn + wn + j*16 + lr;
            const float bvs = bias ? bias[col] : 0.f;
#pragma unroll
            for (int r = 0; r < 4; ++r) {
                float v = acc[i][j][r] + bvs;
                if (act == 1) v = 0.5f * v * (1.0f + erff(v * 0.70710678118f));
                else if (act == 2) v = 1.0f / (1.0f + __expf(-v));
                const size_t idx = (size_t)(rowb + r) * N + col;
                if (res) v += res[idx];
                if (outf32) ((float*)Cv)[idx] = v;
                else        ((u16*)Cv)[idx] = f2bits(v);
            }
        }
    }
}

// ---------- horizontal-fused wl+wg GEMM: gelu(A @ W^T + b), K=512, N=128, bf16 out ----
// blocks [0,256): XL = gelu(L @ WTl^T + bl), M=8192; blocks [256,320): G2 = gelu(G @ WTg^T + bg).
__global__ __launch_bounds__(256)
void gemm_wlg(const u16* __restrict__ L, const u16* __restrict__ G,
              const u16* __restrict__ WTl, const u16* __restrict__ WTg,
              const float* __restrict__ bl, const float* __restrict__ bg,
              u16* __restrict__ XL, u16* __restrict__ G2)
{
    constexpr int K = 512, N = 128;
    const u16* A; const u16* WT; const float* bias; u16* C;
    int bm, bn;
    const int blk = blockIdx.x;
    if (blk < 256) { A = L; WT = WTl; bias = bl; C = XL;
                     bm = (blk & 127) * 64; bn = (blk >> 7) * 64; }
    else           { const int b2 = blk - 256; A = G; WT = WTg; bias = bg; C = G2;
                     bm = (b2 & 31) * 64; bn = (b2 >> 5) * 64; }

    __shared__ u16 As[2][64*64];
    __shared__ u16 Bs[2][64*64];
    const int tid = threadIdx.x, wave = tid >> 6, lane = tid & 63;
    const int wm = (wave >> 1) * 32, wn = (wave & 1) * 32;
    const int lr = lane & 15, quad = lane >> 4;

    const int rowc = lane >> 3;
    const int kgs  = ((lane & 7) ^ (rowc & 7)) * 8;

    auto stage = [&](int buf, int k0) {
#pragma unroll
        for (int t = 0; t < 4; ++t) {
            const int c = wave*4 + t;
            if (c < 8) async16(&As[buf][c*512], A  + (size_t)(bm + c*8 + rowc) * K + k0 + kgs);
            else       async16(&Bs[buf][(c-8)*512], WT + (size_t)(bn + (c-8)*8 + rowc) * K + k0 + kgs);
        }
    };

    f32x4 acc[2][2] = {};
    stage(0, 0);
    __syncthreads();

    for (int ki = 0; ki < 8; ++ki) {
        const int cur = ki & 1;
        if (ki + 1 < 8) stage(cur ^ 1, (ki + 1) * 64);

        bf16x8 af[2][2], bv[2][2];
#pragma unroll
        for (int i = 0; i < 2; ++i) {
            const int rA = wm + i*16 + lr;
            const int sw = rA & 7;
#pragma unroll
            for (int kb = 0; kb < 2; ++kb)
                af[i][kb] = *(const bf16x8*)(As[cur] + rA*64 + (((kb*4 + quad) ^ sw) * 8));
        }
#pragma unroll
        for (int j = 0; j < 2; ++j) {
            const int rB = wn + j*16 + lr;
            const int sw = rB & 7;
#pragma unroll
            for (int kb = 0; kb < 2; ++kb)
                bv[j][kb] = *(const bf16x8*)(Bs[cur] + rB*64 + (((kb*4 + quad) ^ sw) * 8));
        }
#pragma unroll
        for (int i = 0; i < 2; ++i)
#pragma unroll
            for (int j = 0; j < 2; ++j)
#pragma unroll
                for (int kb = 0; kb < 2; ++kb)
                    acc[i][j] = __builtin_amdgcn_mfma_f32_16x16x32_bf16(
                        af[i][kb], bv[j][kb], acc[i][j], 0, 0, 0);
        __syncthreads();
    }

#pragma unroll
    for (int i = 0; i < 2; ++i) {
        const int rowb = bm + wm + i*16 + quad*4;
#pragma unroll
        for (int j = 0; j < 2; ++j) {
            const int col = bn + wn + j*16 + lr;
            const float bvs = bias[col];
#pragma unroll
            for (int r = 0; r < 4; ++r) {
                float v = acc[i][j][r] + bvs;
                v = 0.5f * v * (1.0f + erff(v * 0.70710678118f));
                C[(size_t)(rowb + r) * N + col] = f2bits(v);
            }
        }
    }
}

// ---------- MFMA flash attention, 4-way split-Q: one block per (b,p,h,qquarter) ----------
__global__ __launch_bounds__(256)
void attn_mfma(const u16* __restrict__ qkv, u16* __restrict__ out)
{
    __shared__ u16 Kt[64*72];
    __shared__ u16 Vt[64*72];
    __shared__ u16 Pw[4][16*72];
    const int tid = threadIdx.x;
    const int wave = tid >> 6, lane = tid & 63;
    const int lr = lane & 15, quad = lane >> 4;
    const int bp = blockIdx.x >> 5;          // (b,p)
    const int h  = (blockIdx.x >> 2) & 7;    // head
    const int qq = blockIdx.x & 3;           // query quarter
    const u16* base = qkv + (size_t)bp * NN * (3*DIM);
    const int qo = h*DHEAD, ko = DIM + h*DHEAD, vo = 2*DIM + h*DHEAD;
    const int m0 = qq*64 + wave*16;

    bf16x8 qf[2];
#pragma unroll
    for (int kb = 0; kb < 2; ++kb)
        qf[kb] = *(const bf16x8*)(base + (size_t)(m0 + lr)*(3*DIM) + qo + kb*32 + quad*8);

    f32x4 o[4] = {};
    float mrow[4], lrow[4];
#pragma unroll
    for (int r = 0; r < 4; ++r) { mrow[r] = -1e30f; lrow[r] = 0.f; }

    const int sr = tid >> 3, sc = tid & 7;

    for (int t = 0; t < 4; ++t) {
        __syncthreads();
#pragma unroll
        for (int half = 0; half < 2; ++half) {
            const int key = half*32 + sr;
            const u16* krow = base + (size_t)(t*64 + key)*(3*DIM);
            uint4 kv = *(const uint4*)(krow + ko + sc*8);
            *(uint4*)(Kt + key*72 + sc*8) = kv;
            uint4 vv = *(const uint4*)(krow + vo + sc*8);
            const int d0 = sc*8;
            Vt[(d0+0)*72 + key] = (u16)(vv.x & 0xffffu);
            Vt[(d0+1)*72 + key] = (u16)(vv.x >> 16);
            Vt[(d0+2)*72 + key] = (u16)(vv.y & 0xffffu);
            Vt[(d0+3)*72 + key] = (u16)(vv.y >> 16);
            Vt[(d0+4)*72 + key] = (u16)(vv.z & 0xffffu);
            Vt[(d0+5)*72 + key] = (u16)(vv.z >> 16);
            Vt[(d0+6)*72 + key] = (u16)(vv.w & 0xffffu);
            Vt[(d0+7)*72 + key] = (u16)(vv.w >> 16);
        }
        __syncthreads();

        f32x4 s[4] = {};
        bf16x8 kf[4][2];
#pragma unroll
        for (int j = 0; j < 4; ++j)
#pragma unroll
            for (int kb = 0; kb < 2; ++kb)
                kf[j][kb] = *(const bf16x8*)(Kt + (j*16 + lr)*72 + kb*32 + quad*8);
#pragma unroll
        for (int j = 0; j < 4; ++j)
#pragma unroll
            for (int kb = 0; kb < 2; ++kb)
                s[j] = __builtin_amdgcn_mfma_f32_16x16x32_bf16(
                    qf[kb], kf[j][kb], s[j], 0, 0, 0);

        float alpha[4];
#pragma unroll
        for (int r = 0; r < 4; ++r) {
#pragma unroll
            for (int j = 0; j < 4; ++j) s[j][r] *= 0.125f;
            float mt = fmaxf(fmaxf(s[0][r], s[1][r]), fmaxf(s[2][r], s[3][r]));
#pragma unroll
            for (int off = 1; off <= 8; off <<= 1) mt = fmaxf(mt, __shfl_xor(mt, off));
            const float mn = fmaxf(mrow[r], mt);
            alpha[r] = __expf(mrow[r] - mn);
            mrow[r] = mn;
            float ssum = 0.f;
#pragma unroll
            for (int j = 0; j < 4; ++j) {
                const float p = __expf(s[j][r] - mn);
                s[j][r] = p; ssum += p;
            }
#pragma unroll
            for (int off = 1; off <= 8; off <<= 1) ssum += __shfl_xor(ssum, off);
            lrow[r] = lrow[r]*alpha[r] + ssum;
        }

#pragma unroll
        for (int j = 0; j < 4; ++j)
#pragma unroll
            for (int r = 0; r < 4; ++r)
                Pw[wave][(quad*4 + r)*72 + j*16 + lr] = f2bits(s[j][r]);
        __syncthreads();

#pragma unroll
        for (int jd = 0; jd < 4; ++jd)
#pragma unroll
            for (int r = 0; r < 4; ++r)
                o[jd][r] *= alpha[r];

        bf16x8 af[2], bv[4][2];
#pragma unroll
        for (int kb = 0; kb < 2; ++kb)
            af[kb] = *(const bf16x8*)(Pw[wave] + lr*72 + kb*32 + quad*8);
#pragma unroll
        for (int jd = 0; jd < 4; ++jd)
#pragma unroll
            for (int kb = 0; kb < 2; ++kb)
                bv[jd][kb] = *(const bf16x8*)(Vt + (jd*16 + lr)*72 + kb*32 + quad*8);
#pragma unroll
        for (int jd = 0; jd < 4; ++jd)
#pragma unroll
            for (int kb = 0; kb < 2; ++kb)
                o[jd] = __builtin_amdgcn_mfma_f32_16x16x32_bf16(
                    af[kb], bv[jd][kb], o[jd], 0, 0, 0);
    }

#pragma unroll
    for (int r = 0; r < 4; ++r) {
        const float inv = 1.0f / lrow[r];
        const size_t rowg = (size_t)bp*NN + m0 + quad*4 + r;
#pragma unroll
        for (int jd = 0; jd < 4; ++jd)
            out[rowg*DIM + h*DHEAD + jd*16 + lr] = f2bits(o[jd][r] * inv);
    }
}

// ---------- LayerNorm over DIM=512, fp32 in, bf16 out; one wave per row; float4 ----------
__global__ __launch_bounds__(256)
void ln_kernel(const float* __restrict__ x, const float* __restrict__ g,
               const float* __restrict__ b, u16* __restrict__ y, int rows)
{
    const int wave = threadIdx.x >> 6, lane = threadIdx.x & 63;
    const int row = blockIdx.x * 4 + wave;
    if (row >= rows) return;
    const float4* xr = (const float4*)(x + (size_t)row * DIM);
    float4 v0 = xr[lane], v1 = xr[lane + 64];
    float s  = v0.x+v0.y+v0.z+v0.w + v1.x+v1.y+v1.z+v1.w;
    float s2 = v0.x*v0.x+v0.y*v0.y+v0.z*v0.z+v0.w*v0.w
             + v1.x*v1.x+v1.y*v1.y+v1.z*v1.z+v1.w*v1.w;
#pragma unroll
    for (int off = 32; off; off >>= 1) { s += __shfl_xor(s, off); s2 += __shfl_xor(s2, off); }
    const float mean = s * (1.f/512.f);
    const float var  = s2 * (1.f/512.f) - mean*mean;
    const float rstd = rsqrtf(var + 1e-5f);
    const float4* gp = (const float4*)g; const float4* bp = (const float4*)b;
    float4 g0 = gp[lane], g1 = gp[lane+64], b0 = bp[lane], b1 = bp[lane+64];
    ushort4 o0, o1;
    o0.x = f2bits((v0.x-mean)*rstd*g0.x + b0.x);
    o0.y = f2bits((v0.y-mean)*rstd*g0.y + b0.y);
    o0.z = f2bits((v0.z-mean)*rstd*g0.z + b0.z);
    o0.w = f2bits((v0.w-mean)*rstd*g0.w + b0.w);
    o1.x = f2bits((v1.x-mean)*rstd*g1.x + b1.x);
    o1.y = f2bits((v1.y-mean)*rstd*g1.y + b1.y);
    o1.z = f2bits((v1.z-mean)*rstd*g1.z + b1.z);
    o1.w = f2bits((v1.w-mean)*rstd*g1.w + b1.w);
    ushort4* yr = (ushort4*)(y + (size_t)row * DIM);
    yr[lane] = o0; yr[lane+64] = o1;
}

// ---------- fused BiAttn LN + mean over P: block=(b,n), wave p=0..3 ----------
__global__ __launch_bounds__(256)
void lnmean_kernel(const float* __restrict__ x, const float* __restrict__ g,
                   const float* __restrict__ b, u16* __restrict__ y,
                   u16* __restrict__ G)
{
    __shared__ float T[4][512];
    const int wave = threadIdx.x >> 6, lane = threadIdx.x & 63;
    const int bb = blockIdx.x >> 8, n = blockIdx.x & 255;
    const int row = (bb*PP + wave)*NN + n;
    const float4* xr = (const float4*)(x + (size_t)row * DIM);
    float4 v0 = xr[lane], v1 = xr[lane + 64];
    float s  = v0.x+v0.y+v0.z+v0.w + v1.x+v1.y+v1.z+v1.w;
    float s2 = v0.x*v0.x+v0.y*v0.y+v0.z*v0.z+v0.w*v0.w
             + v1.x*v1.x+v1.y*v1.y+v1.z*v1.z+v1.w*v1.w;
#pragma unroll
    for (int off = 32; off; off >>= 1) { s += __shfl_xor(s, off); s2 += __shfl_xor(s2, off); }
    const float mean = s * (1.f/512.f);
    const float var  = s2 * (1.f/512.f) - mean*mean;
    const float rstd = rsqrtf(var + 1e-5f);
    const float4* gp = (const float4*)g; const float4* bp = (const float4*)b;
    float4 g0 = gp[lane], g1 = gp[lane+64], b0 = bp[lane], b1 = bp[lane+64];
    float4 y0, y1;
    y0.x = (v0.x-mean)*rstd*g0.x + b0.x;
    y0.y = (v0.y-mean)*rstd*g0.y + b0.y;
    y0.z = (v0.z-mean)*rstd*g0.z + b0.z;
    y0.w = (v0.w-mean)*rstd*g0.w + b0.w;
    y1.x = (v1.x-mean)*rstd*g1.x + b1.x;
    y1.y = (v1.y-mean)*rstd*g1.y + b1.y;
    y1.z = (v1.z-mean)*rstd*g1.z + b1.z;
    y1.w = (v1.w-mean)*rstd*g1.w + b1.w;
    ushort4 o0, o1;
    o0.x = f2bits(y0.x); o0.y = f2bits(y0.y); o0.z = f2bits(y0.z); o0.w = f2bits(y0.w);
    o1.x = f2bits(y1.x); o1.y = f2bits(y1.y); o1.z = f2bits(y1.z); o1.w = f2bits(y1.w);
    ushort4* yr = (ushort4*)(y + (size_t)row * DIM);
    yr[lane] = o0; yr[lane+64] = o1;
    *(float4*)&T[wave][lane*4]       = y0;
    *(float4*)&T[wave][256 + lane*4] = y1;
    __syncthreads();
    const int d0 = threadIdx.x;   // 0..255, handles d0 and d0+256
    const float m0 = (T[0][d0]     + T[1][d0]     + T[2][d0]     + T[3][d0])     * 0.25f;
    const float m1 = (T[0][d0+256] + T[1][d0+256] + T[2][d0+256] + T[3][d0+256]) * 0.25f;
    u16* gr = G + ((size_t)bb*NN + n)*DIM;
    gr[d0]       = f2bits(m0);
    gr[d0 + 256] = f2bits(m1);
}

// ---------- fused s_attn + gating + residual + NEXT layer's ln1 ----------
// One wave per row; s in-register; new residual row held in regs -> optional LN out.
__global__ __launch_bounds__(256)
void fuse2_kernel(const float4* __restrict__ xb, const float4* __restrict__ m1,
                  const u16* __restrict__ ca, const u16* __restrict__ xl,
                  const u16* __restrict__ xg, const float* __restrict__ wsv,
                  const float* __restrict__ bs, float4* __restrict__ xa,
                  const float* __restrict__ lng, const float* __restrict__ lnb,
                  u16* __restrict__ lnout)
{
    const int wave = threadIdx.x >> 6, lane = threadIdx.x & 63;
    const int row = blockIdx.x * 4 + wave;
    const int b = row >> 10, n = row & 255;
    const u16* xlr = xl + (size_t)row * RED;
    const u16* xgr = xg + ((size_t)b*NN + n) * RED;
    float s = bits2f(xlr[lane])    * wsv[lane]
            + bits2f(xlr[lane+64]) * wsv[lane+64]
            + bits2f(xgr[lane])    * wsv[RED+lane]
            + bits2f(xgr[lane+64]) * wsv[RED+64+lane];
#pragma unroll
    for (int off = 32; off; off >>= 1) s += __shfl_xor(s, off);
    s = 1.f / (1.f + __expf(-(s + bs[0])));
    const u16* car = ca + ((((size_t)b << 8) + n)*DIM);

    float4 o0, o1;
    {
        const size_t idx = (size_t)row*128 + lane;
        ushort4 cu = *(const ushort4*)(car + lane*4);
        float4 xv = xb[idx], mv = m1[idx];
        o0.x = xv.x + mv.x * bits2f(cu.x) * s;
        o0.y = xv.y + mv.y * bits2f(cu.y) * s;
        o0.z = xv.z + mv.z * bits2f(cu.z) * s;
        o0.w = xv.w + mv.w * bits2f(cu.w) * s;
        xa[idx] = o0;
    }
    {
        const size_t idx = (size_t)row*128 + lane + 64;
        ushort4 cu = *(const ushort4*)(car + (lane + 64)*4);
        float4 xv = xb[idx], mv = m1[idx];
        o1.x = xv.x + mv.x * bits2f(cu.x) * s;
        o1.y = xv.y + mv.y * bits2f(cu.y) * s;
        o1.z = xv.z + mv.z * bits2f(cu.z) * s;
        o1.w = xv.w + mv.w * bits2f(cu.w) * s;
        xa[idx] = o1;
    }

    if (lnout) {   // next layer's ln1, computed from the row already in registers
        float t  = o0.x+o0.y+o0.z+o0.w + o1.x+o1.y+o1.z+o1.w;
        float t2 = o0.x*o0.x+o0.y*o0.y+o0.z*o0.z+o0.w*o0.w
                 + o1.x*o1.x+o1.y*o1.y+o1.z*o1.z+o1.w*o1.w;
#pragma unroll
        for (int off = 32; off; off >>= 1) { t += __shfl_xor(t, off); t2 += __shfl_xor(t2, off); }
        const float mean = t * (1.f/512.f);
        const float var  = t2 * (1.f/512.f) - mean*mean;
        const float rstd = rsqrtf(var + 1e-5f);
        const float4* gp = (const float4*)lng; const float4* bp = (const float4*)lnb;
        float4 g0 = gp[lane], g1 = gp[lane+64], b0 = bp[lane], b1 = bp[lane+64];
        ushort4 q0, q1;
        q0.x = f2bits((o0.x-mean)*rstd*g0.x + b0.x);
        q0.y = f2bits((o0.y-mean)*rstd*g0.y + b0.y);
        q0.z = f2bits((o0.z-mean)*rstd*g0.z + b0.z);
        q0.w = f2bits((o0.w-mean)*rstd*g0.w + b0.w);
        q1.x = f2bits((o1.x-mean)*rstd*g1.x + b1.x);
        q1.y = f2bits((o1.y-mean)*rstd*g1.y + b1.y);
        q1.z = f2bits((o1.z-mean)*rstd*g1.z + b1.z);
        q1.w = f2bits((o1.w-mean)*rstd*g1.w + b1.w);
        ushort4* yr = (ushort4*)(lnout + (size_t)row * DIM);
        yr[lane] = q0; yr[lane+64] = q1;
    }
}

// ---------- host launch ----------
extern "C" void kernel_launch(void* const* d_in, const int* in_sizes, int n_in,
                              void* d_out, int out_size, void* d_ws, size_t ws_size,
                              hipStream_t stream)
{
    const float* x_in  = (const float*)d_in[0];
    const float* ln1_g = (const float*)d_in[1];
    const float* ln1_b = (const float*)d_in[2];
    const float* w_qkv = (const float*)d_in[3];
    const float* w_o   = (const float*)d_in[4];
    const float* b_o   = (const float*)d_in[5];
    const float* ln2_g = (const float*)d_in[6];
    const float* ln2_b = (const float*)d_in[7];
    const float* w1    = (const float*)d_in[8];
    const float* b1    = (const float*)d_in[9];
    const float* w2    = (const float*)d_in[10];
    const float* b2    = (const float*)d_in[11];
    const float* bn_g  = (const float*)d_in[12];
    const float* bn_b  = (const float*)d_in[13];
    const float* wg    = (const float*)d_in[14];
    const float* bg    = (const float*)d_in[15];
    const float* wl    = (const float*)d_in[16];
    const float* bl    = (const float*)d_in[17];
    const float* wc    = (const float*)d_in[18];
    const float* bc    = (const float*)d_in[19];
    const float* wsw   = (const float*)d_in[20];
    const float* bsb   = (const float*)d_in[21];

    char* ws = (char*)d_ws;
    auto alloc = [&](size_t bytes) {
        char* p = ws;
        ws += (bytes + 255) & ~(size_t)255;
        return p;
    };
    float* XA = (float*)alloc(XELEMS * 4);
    float* XB = (float*)alloc(XELEMS * 4);
    float* M1 = (float*)alloc(XELEMS * 4);
    u16*   L  = (u16*)  alloc(XELEMS * 2);
    u16*   Q  = (u16*)  alloc((size_t)ROWS * 3*DIM * 2);
    u16*   H  = (u16*)  alloc((size_t)ROWS * MLPD * 2);
    u16*   G  = (u16*)  alloc((size_t)BB*NN*DIM * 2);
    u16*   G2 = (u16*)  alloc((size_t)BB*NN*RED * 2);
    u16*   XL = (u16*)  alloc((size_t)ROWS*RED * 2);
    u16*   CA = (u16*)  alloc((size_t)BB*NN*DIM * 2);
    // all-layer transposed bf16 weights
    u16* WTqkv = (u16*)alloc((size_t)DEPTH*DIM*3*DIM * 2);
    u16* WTo   = (u16*)alloc((size_t)DEPTH*DIM*DIM * 2);
    u16* WT1   = (u16*)alloc((size_t)DEPTH*DIM*MLPD * 2);
    u16* WT2   = (u16*)alloc((size_t)DEPTH*MLPD*DIM * 2);
    u16* WTl   = (u16*)alloc((size_t)DEPTH*DIM*RED * 2);
    u16* WTg   = (u16*)alloc((size_t)DEPTH*DIM*RED * 2);
    u16* WTc   = (u16*)alloc((size_t)DEPTH*RED*DIM * 2);

    // ---- all weight transposes in ONE launch (segmented grid) ----
    wtrans_fused<<<dim3(3264, 1, DEPTH), 256, 0, stream>>>(
        w_qkv, WTqkv, w_o, WTo, w1, WT1, w2, WT2, wl, WTl, wg, WTg, wc, WTc);

    // layer-0 attention LN (reads the external input); layers 1-3 get L from fuse2
    ln_kernel<<<ROWS/4, 256, 0, stream>>>(x_in, ln1_g, ln1_b, L, ROWS);

    for (int l = 0; l < DEPTH; ++l) {
        const float* Xres = l ? (const float*)XA : x_in;
        // ---- attention block ----
        gemm_db<64,64,64,2,2><<<dim3(128,24), 256, 0, stream>>>(
            L, WTqkv + (size_t)l*DIM*3*DIM, nullptr, nullptr, Q, ROWS, 3*DIM, DIM, 0, 0);
        attn_mfma<<<BB*PP*HEADS*4, 256, 0, stream>>>(Q, L);
        gemm_db<64,64,64,2,2><<<dim3(128,8), 256, 0, stream>>>(
            L, WTo + (size_t)l*DIM*DIM, b_o + l*DIM, Xres, XB, ROWS, DIM, DIM, 0, 1);

        // ---- MLP ----
        ln_kernel<<<ROWS/4, 256, 0, stream>>>(XB, ln2_g + l*DIM, ln2_b + l*DIM, Q, ROWS);
        gemm_db<64,64,32,2,2><<<dim3(128,32), 256, 0, stream>>>(
            Q, WT1 + (size_t)l*DIM*MLPD, b1 + l*MLPD, nullptr, H, ROWS, MLPD, DIM, 1, 0);
        gemm_db<64,64,64,2,2><<<dim3(128,8), 256, 0, stream>>>(
            H, WT2 + (size_t)l*MLPD*DIM, b2 + l*DIM, nullptr, M1, ROWS, DIM, MLPD, 0, 1);

        // ---- BiAttn ----
        lnmean_kernel<<<BB*NN, 256, 0, stream>>>(M1, bn_g + l*DIM, bn_b + l*DIM, L, G);
        gemm_wlg<<<320, 256, 0, stream>>>(L, G, WTl + (size_t)l*DIM*RED,
                                          WTg + (size_t)l*DIM*RED,
                                          bl + l*RED, bg + l*RED, XL, G2);
        gemm_db<64,64,64,2,2><<<dim3(32,8), 256, 0, stream>>>(
            G2, WTc + (size_t)l*RED*DIM, bc + l*DIM, nullptr, CA, BB*NN, DIM, RED, 2, 0);
        // fused s_attn + gating + residual (+ next layer's ln1 for l<3)
        const int last = (l == DEPTH-1);
        fuse2_kernel<<<ROWS/4, 256, 0, stream>>>(
            (const float4*)XB, (const float4*)M1, CA, XL, G2,
            wsw + (size_t)l*2*RED, bsb + l,
            last ? (float4*)d_out : (float4*)XA,
            ln1_g + (l+1)*DIM, ln1_b + (l+1)*DIM,
            last ? nullptr : L);
    }
}